// Round 14
// baseline (1220.356 us; speedup 1.0000x reference)
//
#include <hip/hip_runtime.h>
#include <math.h>

#define BD 16      // fused batches: 2 branches x 8
#define ND 1024
#define KNN 20
#define NEGS 0.2f
#define BNSC 0.99999500003749969482f
#define KSL 8      // key slices for flash-decode attention
#define KPS 128    // keys per slice

__device__ __forceinline__ float leakyf(float y){ return y >= 0.f ? y : NEGS*y; }

// async global->LDS DMA, 16B per lane: dest = wave-uniform base + lane*16 (HW rule),
// src = per-lane. With the tiled x layout the src is lane-CONTIGUOUS (1KB/instr).
__device__ __forceinline__ void gl_lds16(const float* g, float* l){
  __builtin_amdgcn_global_load_lds(
      (const __attribute__((address_space(1))) void*)g,
      (__attribute__((address_space(3))) void*)l, 16, 0, 0);
}

// r14: knn goes to 8 rows/wave (32 rows/block, grid 512). r13 analysis: knn is
// LDS-BW-bound at 1 B/FMA (4 rows/wave); 8 rows -> 0.5 B/FMA, and halved grid
// halves DMA/L2 staging traffic. VGPR rises to ~220 -- safe because occupancy is
// already capped at 2 waves/SIMD by the 64KB LDS double-buffer (m69: 2 waves ok
// up to 256 VGPR). r1/r3/r6 spills happened at the 128-cliff with 4 waves/SIMD.
// acc registers are reused for the select-phase keys (uk). Canary: WRITE_SIZE.

// -------- fused input slice + transpose + xx: tiled write, both branches -------------
template<int C, int CS>
__global__ __launch_bounds__(256) void k_prep(const float* __restrict__ f1,
                                              const float* __restrict__ f2,
                                              float* __restrict__ x,
                                              float* __restrict__ xx, int c0){
  int blk = blockIdx.x;
  int b = blk & 15;
  int n = (blk >> 4)*256 + threadIdx.x;
  const float* feat = (b & 8) ? f2 : f1;
  int b8 = b & 7;
  float v[CS];
  float s = 0.f;
  #pragma unroll
  for (int c = 0; c < C; ++c){
    v[c] = feat[((size_t)(b8*15) + c0 + c)*ND + n];
    s = fmaf(v[c], v[c], s);
  }
  #pragma unroll
  for (int c = C; c < CS; ++c) v[c] = 0.f;
  #pragma unroll
  for (int g = 0; g < CS/4; ++g)
    *(float4*)&x[(size_t)(b*CS + g*4)*ND + (size_t)n*4] =
        make_float4(v[g*4], v[g*4+1], v[g*4+2], v[g*4+3]);
  xx[b*ND + n] = s;
}

// -------- fused gram + exact top-20: DMA ping-pong, 8 rows/wave ----------------------
__global__ __launch_bounds__(256)
void k_knn(const float* __restrict__ x,
    const float* __restrict__ xx, int* __restrict__ idxp, int CS, int nchunk){
  __shared__ __align__(16) float Xc[2][2][4096];   // [buf][quad-array][1024*4] = 64KB
  int b = blockIdx.x & 15;
  int r0 = (blockIdx.x >> 4)*32;                   // 32 rows/block
  int t = threadIdx.x;
  int lane = t & 63;
  int w = __builtin_amdgcn_readfirstlane(t >> 6);  // wave-uniform wave id
  const float* xb = x + (size_t)b*ND*CS;           // tiled [G][n][4]
  float acc[8][16];
  #pragma unroll
  for (int j = 0; j < 8; ++j)
    #pragma unroll
    for (int q = 0; q < 16; ++q) acc[j][q] = 0.f;

  // stage chunk ch (quads 2ch, 2ch+1) into buffer buf via DMA; zero-fill padded quads
  auto stage = [&](int buf, int ch){
    int g0 = 2*ch, g1 = 2*ch + 1;
    bool v1 = (g1*4 < CS);                       // g0 always valid by construction
    #pragma unroll
    for (int i = 0; i < 4; ++i){
      int m = i*256 + t;
      unsigned ub = (unsigned)((i*256 + (w << 6))*4);   // wave-uniform elem base
      gl_lds16(&xb[((size_t)g0*ND + m)*4], &Xc[buf][0][ub]);
      if (v1) gl_lds16(&xb[((size_t)g1*ND + m)*4], &Xc[buf][1][ub]);
      else    *(float4*)&Xc[buf][1][m*4] = make_float4(0.f,0.f,0.f,0.f);
    }
  };

  stage(0, 0);
  __syncthreads();              // drains vmcnt: buffer 0 ready
  int cur = 0;
  for (int ch = 0; ch < nchunk; ++ch){
    bool more = (ch + 1 < nchunk);
    if (more) stage(cur ^ 1, ch + 1);   // DMA in flight during the FMA phase
    // row fragments from LDS (rows r0..r0+31 are columns; uniform-addr broadcast)
    float4 rv0[8], rv1[8];
    #pragma unroll
    for (int j = 0; j < 8; ++j){
      rv0[j] = *(const float4*)&Xc[cur][0][(r0 + w*8 + j)*4];
      rv1[j] = *(const float4*)&Xc[cur][1][(r0 + w*8 + j)*4];
    }
    #pragma unroll
    for (int q = 0; q < 16; ++q){
      float4 cv0 = *(const float4*)&Xc[cur][0][(q*64 + lane)*4];
      float4 cv1 = *(const float4*)&Xc[cur][1][(q*64 + lane)*4];
      #pragma unroll
      for (int j = 0; j < 8; ++j){
        float s = acc[j][q];   // strict sequential col order: bitwise-stable result
        s = fmaf(rv0[j].x, cv0.x, s); s = fmaf(rv0[j].y, cv0.y, s);
        s = fmaf(rv0[j].z, cv0.z, s); s = fmaf(rv0[j].w, cv0.w, s);
        s = fmaf(rv1[j].x, cv1.x, s); s = fmaf(rv1[j].y, cv1.y, s);
        s = fmaf(rv1[j].z, cv1.z, s); s = fmaf(rv1[j].w, cv1.w, s);
        acc[j][q] = s;
      }
    }
    if (more){
      __syncthreads();   // all waves done reading cur; my ch+1 DMA drained (had
      cur ^= 1;          // the full FMA phase to land) -> idle buf ready
    }
  }
  // transform to negdist = 2*dot - xx_r - xx_m, then to sortable uints (in place:
  // uk reuses acc's registers -- select-phase peak stays low)
  float xxm[16];
  #pragma unroll
  for (int q = 0; q < 16; ++q) xxm[q] = xx[b*ND + q*64 + lane];
  unsigned uk[8][16];
  #pragma unroll
  for (int j = 0; j < 8; ++j){
    float xr = xx[b*ND + r0 + w*8 + j];
    #pragma unroll
    for (int q = 0; q < 16; ++q){
      float f = 2.f*acc[j][q] - xr - xxm[q];
      unsigned bv = __float_as_uint(f);
      uk[j][q] = (bv & 0x80000000u) ? ~bv : (bv | 0x80000000u);  // order-preserving
    }
  }
  // radix binary search for T = 20th-largest key per row (bit 31: only the diagonal
  // reaches it, count==1<20 always -> skip). Early exit at exact count==20 (set-equal).
  unsigned pref[8] = {0u,0u,0u,0u,0u,0u,0u,0u};
  unsigned done = 0u;
  #pragma unroll 1
  for (int bit = 30; bit >= 0; --bit){
    #pragma unroll
    for (int u = 0; u < 8; ++u){
      if (done & (1u << u)) continue;           // wave-uniform (ballot-derived)
      unsigned cand = pref[u] | (1u << bit);
      int c = 0;
      #pragma unroll
      for (int q = 0; q < 16; ++q)
        c += (int)__popcll(__ballot(uk[u][q] >= cand));
      if (c >= KNN){
        pref[u] = cand;
        if (c == KNN) done |= (1u << u);
      }
    }
    if (done == 255u) break;
  }
  // emit: all keys > T, plus lowest-global-index keys == T to fill to 20
  unsigned long long mlt = (1ull << lane) - 1ull;   // lanes below me
  #pragma unroll
  for (int u = 0; u < 8; ++u){
    unsigned T = pref[u];
    int cg = 0;
    #pragma unroll
    for (int q = 0; q < 16; ++q) cg += (int)__popcll(__ballot(uk[u][q] > T));
    int need_eq = KNN - cg;                          // >= 1 by construction
    int* op = &idxp[((size_t)(b*ND + r0 + w*8 + u))*KNN];
    int run_gt = 0, run_eq = 0;
    #pragma unroll
    for (int q = 0; q < 16; ++q){
      unsigned k = uk[u][q];
      unsigned long long bg = __ballot(k > T);
      unsigned long long be = __ballot(k == T);
      if (k > T) op[run_gt + (int)__popcll(bg & mlt)] = q*64 + lane;
      if (k == T){
        int r = run_eq + (int)__popcll(be & mlt);
        if (r < need_eq) op[cg + r] = q*64 + lane;
      }
      run_gt += (int)__popcll(bg);
      run_eq += (int)__popcll(be);
    }
  }
}

// ------ phase A (register-blocked), tiled x, 16 batches (grid 512 = 2 blocks/CU) -----
template<int O>
__global__ __launch_bounds__(256) void k_phaseA(const float* __restrict__ x,
    const float* __restrict__ W, const float* __restrict__ bias,
    const float* __restrict__ gamma, const float* __restrict__ beta,
    float* __restrict__ zs, float* __restrict__ ccv, int C, int XS){
  constexpr int TO = O/16;
  constexpr int WP = O + 4;
  __shared__ float W1s[32*WP];
  __shared__ float dWs[32*WP];
  __shared__ float Xs[32*33];
  int blk = blockIdx.x;
  int b = blk & 15, n0 = (blk >> 4)*32;
  int t = threadIdx.x;
  int ot = t & 15, nt = t >> 4;
  int obase = ot*TO;
  int nl = nt*2;
  float az[TO][2] = {}, ac[TO][2] = {};
  for (int cc = 0; cc < C; cc += 32){
    int KC = (C - cc < 32) ? (C - cc) : 32;
    int NG = (KC + 3) >> 2;
    for (int i = t; i < O*KC; i += 256){
      int o = i % O, c = i / O;
      float w1 = W[(size_t)o*2*C + cc + c];
      float w2 = W[(size_t)o*2*C + C + cc + c];
      W1s[c*WP + o] = w1;
      dWs[c*WP + o] = w2 - w1;
    }
    for (int i = t; i < 32*NG; i += 256){
      int row = i & 31, g = i >> 5;
      float4 v = *(const float4*)&x[(size_t)(b*XS + cc + g*4)*ND + (size_t)(n0+row)*4];
      Xs[(g*4+0)*33 + row] = v.x;
      Xs[(g*4+1)*33 + row] = v.y;
      Xs[(g*4+2)*33 + row] = v.z;
      Xs[(g*4+3)*33 + row] = v.w;
    }
    __syncthreads();
    for (int c = 0; c < KC; ++c){
      float xv0 = Xs[c*33 + nl];
      float xv1 = Xs[c*33 + nl + 1];
      #pragma unroll
      for (int i = 0; i < TO; ++i){
        float w1 = W1s[c*WP + obase + i];
        float dw = dWs[c*WP + obase + i];
        az[i][0] = fmaf(w1, xv0, az[i][0]);
        az[i][1] = fmaf(w1, xv1, az[i][1]);
        ac[i][0] = fmaf(dw, xv0, ac[i][0]);
        ac[i][1] = fmaf(dw, xv1, ac[i][1]);
      }
    }
    __syncthreads();
  }
  #pragma unroll
  for (int i = 0; i < TO; ++i){
    int o = obase + i;
    float alpha = gamma[o]*BNSC;
    float bb = bias[o], be = beta[o];
    #pragma unroll
    for (int q = 0; q < 2; ++q){
      int n = n0 + nl + q;
      size_t off = ((size_t)b*ND + n)*O + o;
      zs[off]  = az[i][q]*alpha;
      ccv[off] = fmaf(ac[i][q] + bb, alpha, be);
    }
  }
}

// ------ phase B: out = max_k leaky(zs[idx_k]+cc); TILED knn-layout writes ------------
template<bool DOXX, bool TILED>
__global__ __launch_bounds__(256) void k_phaseB(const float* __restrict__ zs,
    const float* __restrict__ ccv, const int* __restrict__ idxp,
    float* __restrict__ outp, float* __restrict__ xxout,
    int O, int ostride, int ooff){
  int t = threadIdx.x;
  int lane = t & 63, w = t >> 6;
  int b = blockIdx.x & 15;
  int n = (blockIdx.x >> 4)*4 + w;
  int gn = (b << 10) + n;
  int mm[KNN];
  const int* ip = idxp + (size_t)gn*KNN;
  #pragma unroll
  for (int k = 0; k < KNN; ++k) mm[k] = ip[k];
  float sq = 0.f;
  for (int o = lane; o < O; o += 64){
    float cvv = ccv[(size_t)gn*O + o];
    float mx = -INFINITY;
    #pragma unroll 4
    for (int k = 0; k < KNN; ++k){
      float v = leakyf(zs[((size_t)(b*ND) + mm[k])*O + o] + cvv);
      mx = fmaxf(mx, v);
    }
    if (TILED)
      outp[(size_t)(b*O + (o & ~3))*ND + (size_t)n*4 + (o & 3)] = mx;
    else
      outp[(size_t)gn*ostride + ooff + o] = mx;
    if (DOXX) sq = fmaf(mx, mx, sq);
  }
  if (DOXX){
    #pragma unroll
    for (int off = 32; off; off >>= 1) sq += __shfl_down(sq, off);
    if (lane == 0) xxout[gn] = sq;
  }
}

// --------- qkv: LDS-tiled GEMM [16K x 64] @ [64 x 192] + bias (r13 proven) -----------
__global__ __launch_bounds__(256) void k_lin(const float* __restrict__ in,
    const float* __restrict__ Wm, const float* __restrict__ bias,
    float* __restrict__ outp){
  __shared__ float Ws[64*196];    // 50.2 KB: Ws[c*196 + o]
  __shared__ float Xs[64*33];     // 8.4 KB:  Xs[c*33 + row]
  int blk = blockIdx.x;
  int b = blk & 15, n0 = (blk >> 4)*32;
  int bn0 = (b << 10) + n0;
  int t = threadIdx.x;
  int ot = t & 15, nt = t >> 4;
  int obase = ot*12;
  int nl = nt*2;
  // stage W transposed: coalesced global read Wm[o*64+c] (i contiguous)
  for (int i = t; i < 192*64; i += 256){
    int c = i & 63, o = i >> 6;
    Ws[c*196 + o] = Wm[i];
  }
  // stage A-tile: coalesced float4 rows -> Xs[c][row]
  for (int i = t; i < 32*16; i += 256){
    int row = i >> 4, c4 = i & 15;
    float4 v = *(const float4*)&in[((size_t)(bn0 + row))*64 + c4*4];
    Xs[(c4*4+0)*33 + row] = v.x;
    Xs[(c4*4+1)*33 + row] = v.y;
    Xs[(c4*4+2)*33 + row] = v.z;
    Xs[(c4*4+3)*33 + row] = v.w;
  }
  __syncthreads();
  float acc[12][2];
  #pragma unroll
  for (int i = 0; i < 12; ++i){
    float bb = bias[obase + i];
    acc[i][0] = bb; acc[i][1] = bb;     // bias first, then c ascending == old order
  }
  for (int c = 0; c < 64; ++c){
    float xv0 = Xs[c*33 + nl];
    float xv1 = Xs[c*33 + nl + 1];
    #pragma unroll
    for (int i = 0; i < 12; ++i){
      float wv = Ws[c*196 + obase + i];
      acc[i][0] = fmaf(wv, xv0, acc[i][0]);
      acc[i][1] = fmaf(wv, xv1, acc[i][1]);
    }
  }
  #pragma unroll
  for (int q = 0; q < 2; ++q){
    float* op = &outp[(size_t)(bn0 + nl + q)*192 + obase];
    #pragma unroll
    for (int v4 = 0; v4 < 3; ++v4)
      *(float4*)&op[v4*4] = make_float4(acc[v4*4+0][q], acc[v4*4+1][q],
                                        acc[v4*4+2][q], acc[v4*4+3][q]);
  }
}

// ------- flash-decode attention (no-max exp): 2 heads/block ---------------------------
__global__ __launch_bounds__(256, 1) void k_attn_part(const float* __restrict__ qkv,
    float* __restrict__ pl, float* __restrict__ pacc){
  __shared__ __align__(16) float Ks[2][KPS*8];
  __shared__ __align__(16) float Vs[2][KPS*8];
  int blk = blockIdx.x;                // b(16, low bits) x ksl(8) x hp(4) = 512 blocks
  int b = blk & 15; int ksl = (blk >> 4) & 7; int hp = blk >> 7;
  int t = threadIdx.x;
  int hh = t >> 7;                     // wave-uniform head select within pair
  int h = hp*2 + hh;
  int lq = t & 127;
  for (int i = t; i < 2*KPS*8; i += 256){
    int hi = (i >= KPS*8) ? 1 : 0;
    int r = i - hi*KPS*8;
    int m = r >> 3, dd = r & 7;
    size_t base = ((size_t)b*ND + ksl*KPS + m)*192 + (hp*2 + hi)*8 + dd;
    Ks[hi][r] = qkv[base + 64];
    Vs[hi][r] = qkv[base + 128];
  }
  __syncthreads();
  const float scale = 0.35355339059327373f;
  float q[8][8];
  #pragma unroll
  for (int u = 0; u < 8; ++u){
    int n = u*128 + lq;
    const float4* qp = (const float4*)(qkv + ((size_t)b*ND + n)*192 + h*8);
    float4 q0 = qp[0], q1 = qp[1];
    q[u][0]=q0.x*scale; q[u][1]=q0.y*scale; q[u][2]=q0.z*scale; q[u][3]=q0.w*scale;
    q[u][4]=q1.x*scale; q[u][5]=q1.y*scale; q[u][6]=q1.z*scale; q[u][7]=q1.w*scale;
  }
  float l[8] = {};
  float acc[8][8] = {};
  for (int m = 0; m < KPS; ++m){
    float4 k0 = *(const float4*)&Ks[hh][m*8];
    float4 k1 = *(const float4*)&Ks[hh][m*8+4];
    float4 v0 = *(const float4*)&Vs[hh][m*8];
    float4 v1 = *(const float4*)&Vs[hh][m*8+4];
    #pragma unroll
    for (int u = 0; u < 8; ++u){
      float s;
      s = q[u][0]*k0.x;           s = fmaf(q[u][1], k0.y, s);
      s = fmaf(q[u][2], k0.z, s); s = fmaf(q[u][3], k0.w, s);
      s = fmaf(q[u][4], k1.x, s); s = fmaf(q[u][5], k1.y, s);
      s = fmaf(q[u][6], k1.z, s); s = fmaf(q[u][7], k1.w, s);
      float p = __expf(s);        // scores tiny: exp-without-max is safe; merge = sum
      l[u] += p;
      acc[u][0] = fmaf(p, v0.x, acc[u][0]);
      acc[u][1] = fmaf(p, v0.y, acc[u][1]);
      acc[u][2] = fmaf(p, v0.z, acc[u][2]);
      acc[u][3] = fmaf(p, v0.w, acc[u][3]);
      acc[u][4] = fmaf(p, v1.x, acc[u][4]);
      acc[u][5] = fmaf(p, v1.y, acc[u][5]);
      acc[u][6] = fmaf(p, v1.z, acc[u][6]);
      acc[u][7] = fmaf(p, v1.w, acc[u][7]);
    }
  }
  #pragma unroll
  for (int u = 0; u < 8; ++u){
    int n = u*128 + lq;
    size_t pidx = (((size_t)(b*8 + h))*8 + ksl)*ND + n;
    pl[pidx] = l[u];
    float4* ap = (float4*)&pacc[pidx*8];
    ap[0] = make_float4(acc[u][0], acc[u][1], acc[u][2], acc[u][3]);
    ap[1] = make_float4(acc[u][4], acc[u][5], acc[u][6], acc[u][7]);
  }
}

// ------- flash-decode combine: plain sums --------------------------------------------
__global__ __launch_bounds__(256) void k_attn_comb(const float* __restrict__ pl,
    const float* __restrict__ pacc, float* __restrict__ attno){
  int b = blockIdx.x & 15;
  int inner = (blockIdx.x >> 4)*256 + threadIdx.x;   // 0..8191 = h(8) x n(1024)
  int h = inner >> 10; int n = inner & 1023;
  int bh = b*8 + h;
  float L = 0.f;
  float o[8] = {};
  #pragma unroll
  for (int s = 0; s < KSL; ++s){
    size_t pidx = ((size_t)bh*8 + s)*ND + n;
    L += pl[pidx];
    const float4* ap = (const float4*)&pacc[pidx*8];
    float4 a0 = ap[0], a1 = ap[1];
    o[0] += a0.x; o[1] += a0.y; o[2] += a0.z; o[3] += a0.w;
    o[4] += a1.x; o[5] += a1.y; o[6] += a1.z; o[7] += a1.w;
  }
  float inv = 1.f/L;
  float4* dst = (float4*)&attno[((size_t)b*ND + n)*64 + h*8];
  dst[0] = make_float4(o[0]*inv, o[1]*inv, o[2]*inv, o[3]*inv);
  dst[1] = make_float4(o[4]*inv, o[5]*inv, o[6]*inv, o[7]*inv);
}

// ------- out-proj + pair-mean: emb[bn,f] = 0.5*(proj[2f]+proj[2f+1]) -----------------
__global__ __launch_bounds__(256) void k_projmean(const float* __restrict__ attno,
    const float* __restrict__ Wo, const float* __restrict__ bo,
    float* __restrict__ emb){
  int b = blockIdx.x & 15;
  int inner = (blockIdx.x >> 4)*256 + threadIdx.x;   // 0..32767 = n(1024) x f(32)
  int n = inner >> 5; int f = inner & 31;
  int bn = (b << 10) + n;
  const float4* ip = (const float4*)(attno + (size_t)bn*64);
  int o0 = 2*f, o1 = 2*f + 1;
  const float4* w0 = (const float4*)(Wo + (size_t)o0*64);
  const float4* w1 = (const float4*)(Wo + (size_t)o1*64);
  float s0 = bo[o0], s1 = bo[o1];
  #pragma unroll
  for (int c = 0; c < 16; ++c){
    float4 a = ip[c], u = w0[c], v = w1[c];
    s0 = fmaf(a.x,u.x,s0); s0 = fmaf(a.y,u.y,s0); s0 = fmaf(a.z,u.z,s0); s0 = fmaf(a.w,u.w,s0);
    s1 = fmaf(a.x,v.x,s1); s1 = fmaf(a.y,v.y,s1); s1 = fmaf(a.z,v.z,s1); s1 = fmaf(a.w,v.w,s1);
  }
  emb[(size_t)bn*32 + f] = 0.5f*(s0 + s1);
}

// ---------------- fused attention pool: one block per b16 ----------------------------
// sout base = out+8; b16*ND+n == br*(8*ND)+b8*ND+n (branch output slices contiguous)
__global__ __launch_bounds__(256) void k_poolfuse(const float* __restrict__ emb,
    const float* __restrict__ attw, float* __restrict__ sout,
    float* __restrict__ pooled){
  __shared__ float part[8][32];
  __shared__ float meanv[32];
  __shared__ float gv[32];
  __shared__ float sc[ND];
  int b = blockIdx.x, t = threadIdx.x;
  int f = t & 31, j = t >> 5;
  const float* eb = emb + (size_t)b*ND*32;
  float s = 0.f;
  for (int n = j; n < ND; n += 8) s += eb[n*32 + f];
  part[j][f] = s;
  __syncthreads();
  if (t < 32){
    float m = 0.f;
    for (int j2 = 0; j2 < 8; ++j2) m += part[j2][t];
    meanv[t] = m * (1.f/ND);
  }
  __syncthreads();
  if (t < 32){
    float acc = 0.f;
    for (int f2 = 0; f2 < 32; ++f2) acc = fmaf(meanv[f2], attw[f2*32 + t], acc);
    gv[t] = tanhf(acc);
  }
  __syncthreads();
  for (int n = t; n < ND; n += 256){
    const float4* ep = (const float4*)(eb + n*32);
    float acc = 0.f;
    #pragma unroll
    for (int f4 = 0; f4 < 8; ++f4){
      float4 e = ep[f4];
      acc = fmaf(e.x, gv[f4*4+0], acc);
      acc = fmaf(e.y, gv[f4*4+1], acc);
      acc = fmaf(e.z, gv[f4*4+2], acc);
      acc = fmaf(e.w, gv[f4*4+3], acc);
    }
    float sg = 1.f/(1.f + __expf(-acc));
    sout[(size_t)b*ND + n] = sg;
    sc[n] = sg;
  }
  __syncthreads();
  float pacc = 0.f;
  for (int n = j; n < ND; n += 8) pacc = fmaf(eb[n*32 + f], sc[n], pacc);
  part[j][f] = pacc;
  __syncthreads();
  if (t < 32){
    float m = 0.f;
    for (int j2 = 0; j2 < 8; ++j2) m += part[j2][t];
    pooled[b*32 + t] = m;
  }
}

// ---------------- NTN head: LDS-staged weights (2-phase, 32KB each) ------------------
__global__ __launch_bounds__(256) void k_head(const float* __restrict__ p1,
    const float* __restrict__ p2, const float* __restrict__ ntnw,
    const float* __restrict__ ntnv, const float* __restrict__ ntnb,
    const float* __restrict__ fc1w, const float* __restrict__ fc1b,
    const float* __restrict__ scw, const float* __restrict__ scb,
    float* __restrict__ outscore){
  __shared__ __align__(16) float Wl[8192];
  __shared__ float Vl[512];
  __shared__ float F1[256];
  __shared__ float ds[8][32];
  __shared__ float tv[8][16];
  __shared__ float hv[8][16];
  int t = threadIdx.x;
  {
    int b = t >> 5, f = t & 31;
    ds[b][f] = p1[b*32+f] - p2[b*32+f];
  }
  for (int i = t; i < 512; i += 256) Vl[i] = ntnv[i];
  if (t < 256) F1[t] = fc1w[t];
  float acc = 0.f;
  for (int ph = 0; ph < 2; ++ph){
    __syncthreads();
    {
      const float4* src = (const float4*)(ntnw + ph*8192);
      float4* dst = (float4*)Wl;
      for (int i = t; i < 2048; i += 256) dst[i] = src[i];
    }
    __syncthreads();
    if (t < 128){
      int b = t >> 4, tt = t & 15;
      for (int fi = 0; fi < 16; ++fi){
        float df = ds[b][ph*16 + fi];
        #pragma unroll 8
        for (int gg = 0; gg < 32; ++gg)
          acc = fmaf(df*ds[b][gg], Wl[(fi*32+gg)*16 + tt], acc);
      }
    }
  }
  if (t < 128){
    int b = t >> 4, tt = t & 15;
    acc += ntnb[tt];
    for (int gg = 0; gg < 32; ++gg) acc = fmaf(ds[b][gg], Vl[tt*32+gg], acc);
    tv[b][tt] = fmaxf(acc, 0.f);
  }
  __syncthreads();
  if (t < 128){
    int b = t >> 4, i = t & 15;
    float a2 = fc1b[i];
    for (int kk = 0; kk < 16; ++kk) a2 = fmaf(tv[b][kk], F1[i*16+kk], a2);
    hv[b][i] = fmaxf(a2, 0.f);
  }
  __syncthreads();
  if (t < 8){
    float a3 = scb[0];
    for (int i = 0; i < 16; ++i) a3 = fmaf(hv[t][i], scw[i], a3);
    outscore[t] = 1.f/(1.f + __expf(-a3));
  }
}

// =====================================================================================
extern "C" void kernel_launch(void* const* d_in, const int* in_sizes, int n_in,
                              void* d_out, int out_size, void* d_ws, size_t ws_size,
                              hipStream_t stream) {
  auto F = [&](int i){ return (const float*)d_in[i]; };
  const float* f1 = F(0); const float* f2 = F(1);
  const float* cw[3] = { F(2), F(6), F(10) };
  const float* cb[3] = { F(3), F(7), F(11) };
  const float* cg[3] = { F(4), F(8), F(12) };
  const float* cB[3] = { F(5), F(9), F(13) };
  const float* sw[3] = { F(14), F(18), F(22) };
  const float* sb[3] = { F(15), F(19), F(23) };
  const float* sg[3] = { F(16), F(20), F(24) };
  const float* sB[3] = { F(17), F(21), F(25) };
  const float* mha_wi = F(26); const float* mha_bi = F(27);
  const float* mha_wo = F(28); const float* mha_bo = F(29);
  const float* att_w  = F(30);
  const float* ntn_w  = F(31); const float* ntn_v = F(32); const float* ntn_b = F(33);
  const float* fc1_w  = F(34); const float* fc1_b = F(35);
  const float* sc_w   = F(36); const float* sc_b  = F(37);
  float* out = (float*)d_out;

  char* ws = (char*)d_ws;
  const size_t MB = 1 << 20;
  // Edge-conv segment [0, 35MB) -- dead before the MHA phase begins:
  float* xA   = (float*)(ws + 0*MB);        // 8 MB  (16 x 1024 x 128 x 4)
  float* xB   = (float*)(ws + 8*MB);        // 8 MB
  float* zs   = (float*)(ws + 16*MB);       // 8 MB
  float* cvb  = (float*)(ws + 24*MB);       // 8 MB
  int*   idxb = (int*)  (ws + 32*MB);       // 1.25 MB
  float* xxb  = (float*)(ws + 34*MB);       // 64 KB
  float* fuse = (float*)(ws + 35*MB);       // 4 MB  [dies after k_lin]
  // MHA segment aliases the dead edge-conv buffers (stream-sequential, safe):
  float* qkv   = (float*)(ws + 0*MB);       // 12 MB over xA + xB-low   (dead)
  float* plb   = (float*)(ws + 12*MB);      // 4 MB  over xB-high       (dead)
  float* paccb = (float*)(ws + 16*MB);      // 32 MB over zs,cvb,idx,xx,fuse (dead)
  float* attno = (float*)(ws + 48*MB);      // 4 MB fresh
  float* emb   = (float*)(ws + 52*MB);      // 2 MB fresh
  float* pooled= (float*)(ws + 54*MB);      // 2 KB
  (void)ws_size;

  auto knn = [&](const float* xin, int CS, int nch8){
    k_knn<<<BD*32, 256, 0, stream>>>(xin, xxb, idxb, CS, nch8);
  };
  auto phA = [&](const float* xin, int C, int XS, int O, const float* W, const float* bb,
                 const float* gg, const float* be){
    if (O == 64)       k_phaseA<64> <<<BD*32, 256, 0, stream>>>(xin, W, bb, gg, be, zs, cvb, C, XS);
    else if (O == 128) k_phaseA<128><<<BD*32, 256, 0, stream>>>(xin, W, bb, gg, be, zs, cvb, C, XS);
    else               k_phaseA<32> <<<BD*32, 256, 0, stream>>>(xin, W, bb, gg, be, zs, cvb, C, XS);
  };

  for (int part = 0; part < 2; ++part){
    const float* const* Wl = part ? sw : cw;
    const float* const* bl = part ? sb : cb;
    const float* const* gl = part ? sg : cg;
    const float* const* Bl = part ? sB : cB;
    int C0 = part ? 12 : 3;
    int CS0 = part ? 12 : 4;
    // layer 0: C0 -> 64 (both branches at once: 16 batches)
    if (part) k_prep<12,12><<<BD*ND/256, 256, 0, stream>>>(f1, f2, xA, xxb, 3);
    else      k_prep<3, 4> <<<BD*ND/256, 256, 0, stream>>>(f1, f2, xA, xxb, 0);
    knn(xA, CS0, part ? 2 : 1);
    phA(xA, C0, CS0, 64, Wl[0], bl[0], gl[0], Bl[0]);
    k_phaseB<true,true><<<BD*ND/4, 256, 0, stream>>>(zs, cvb, idxb, xB, xxb, 64, 0, 0);
    // layer 1: 64 -> 128 (xx produced by phaseB)
    knn(xB, 64, 8);
    phA(xB, 64, 64, 128, Wl[1], bl[1], gl[1], Bl[1]);
    k_phaseB<true,true><<<BD*ND/4, 256, 0, stream>>>(zs, cvb, idxb, xA, xxb, 128, 0, 0);
    // layer 2: 128 -> 32, written into fuse at column offset (row-major)
    knn(xA, 128, 16);
    phA(xA, 128, 128, 32, Wl[2], bl[2], gl[2], Bl[2]);
    k_phaseB<false,false><<<BD*ND/4, 256, 0, stream>>>(zs, cvb, idxb, fuse, nullptr, 32, 64, part*32);
  }
  // MHA (flash-decode, no-max exp) over all 16 batches
  k_lin<<<BD*32, 256, 0, stream>>>(fuse, mha_wi, mha_bi, qkv);
  k_attn_part<<<BD*4*KSL, 256, 0, stream>>>(qkv, plb, paccb);
  k_attn_comb<<<(BD*8*ND)/256, 256, 0, stream>>>(plb, paccb, attno);
  k_projmean<<<(BD*ND*32)/256, 256, 0, stream>>>(attno, mha_wo, mha_bo, emb);
  // fused attention pool (sout slices are contiguous across the 16 batches)
  k_poolfuse<<<BD, 256, 0, stream>>>(emb, att_w, out + 8, pooled);
  k_head<<<1, 256, 0, stream>>>(pooled, pooled + 256, ntn_w, ntn_v, ntn_b,
                                fc1_w, fc1_b, sc_w, sc_b, out);
}

// Round 15
// 1035.609 us; speedup vs baseline: 1.1784x; 1.1784x over previous
//
#include <hip/hip_runtime.h>
#include <math.h>

#define BD 16      // fused batches: 2 branches x 8
#define ND 1024
#define KNN 20
#define NEGS 0.2f
#define BNSC 0.99999500003749969482f
#define KSL 8      // key slices for flash-decode attention
#define KPS 128    // keys per slice

__device__ __forceinline__ float leakyf(float y){ return y >= 0.f ? y : NEGS*y; }

// async global->LDS DMA, 16B per lane: dest = wave-uniform base + lane*16 (HW rule),
// src = per-lane. With the tiled x layout the src is lane-CONTIGUOUS (1KB/instr).
__device__ __forceinline__ void gl_lds16(const float* g, float* l){
  __builtin_amdgcn_global_load_lds(
      (const __attribute__((address_space(1))) void*)g,
      (__attribute__((address_space(3))) void*)l, 16, 0, 0);
}

// r15: knn keeps r13's proven per-wave shape (4 rows/wave, VGPR ~120) but goes to
// 8-wave (512-thr) blocks -> 16 waves/CU = 4 waves/SIMD (double r13). r14 lesson:
// knn is issue/latency-bound at 2 waves/SIMD (VALUBusy 48%), NOT LDS-BW-bound --
// more rows/wave lengthened serial stretches and dropped occupancy (158us). This
// variant raises TLP with IDENTICAL total LDS traffic (unlike r2, which halved
// rows/wave and doubled traffic). Two independent blocks still overlap barriers.

// -------- fused input slice + transpose + xx: tiled write, both branches -------------
template<int C, int CS>
__global__ __launch_bounds__(256) void k_prep(const float* __restrict__ f1,
                                              const float* __restrict__ f2,
                                              float* __restrict__ x,
                                              float* __restrict__ xx, int c0){
  int blk = blockIdx.x;
  int b = blk & 15;
  int n = (blk >> 4)*256 + threadIdx.x;
  const float* feat = (b & 8) ? f2 : f1;
  int b8 = b & 7;
  float v[CS];
  float s = 0.f;
  #pragma unroll
  for (int c = 0; c < C; ++c){
    v[c] = feat[((size_t)(b8*15) + c0 + c)*ND + n];
    s = fmaf(v[c], v[c], s);
  }
  #pragma unroll
  for (int c = C; c < CS; ++c) v[c] = 0.f;
  #pragma unroll
  for (int g = 0; g < CS/4; ++g)
    *(float4*)&x[(size_t)(b*CS + g*4)*ND + (size_t)n*4] =
        make_float4(v[g*4], v[g*4+1], v[g*4+2], v[g*4+3]);
  xx[b*ND + n] = s;
}

// -------- fused gram + exact top-20: DMA ping-pong, 8 waves x 4 rows -----------------
__global__ __launch_bounds__(512)
void k_knn(const float* __restrict__ x,
    const float* __restrict__ xx, int* __restrict__ idxp, int CS, int nchunk){
  __shared__ __align__(16) float Xc[2][2][4096];   // [buf][quad-array][1024*4] = 64KB
  int b = blockIdx.x & 15;
  int r0 = (blockIdx.x >> 4)*32;                   // 32 rows/block (8 waves x 4)
  int t = threadIdx.x;
  int lane = t & 63;
  int w = __builtin_amdgcn_readfirstlane(t >> 6);  // wave-uniform wave id 0..7
  const float* xb = x + (size_t)b*ND*CS;           // tiled [G][n][4]
  float acc[4][16];
  #pragma unroll
  for (int j = 0; j < 4; ++j)
    #pragma unroll
    for (int q = 0; q < 16; ++q) acc[j][q] = 0.f;

  // stage chunk ch (quads 2ch, 2ch+1) into buffer buf via DMA; zero-fill padded quads
  auto stage = [&](int buf, int ch){
    int g0 = 2*ch, g1 = 2*ch + 1;
    bool v1 = (g1*4 < CS);                       // g0 always valid by construction
    #pragma unroll
    for (int i = 0; i < 2; ++i){
      int m = i*512 + t;
      unsigned ub = (unsigned)((i*512 + (w << 6))*4);   // wave-uniform elem base
      gl_lds16(&xb[((size_t)g0*ND + m)*4], &Xc[buf][0][ub]);
      if (v1) gl_lds16(&xb[((size_t)g1*ND + m)*4], &Xc[buf][1][ub]);
      else    *(float4*)&Xc[buf][1][m*4] = make_float4(0.f,0.f,0.f,0.f);
    }
  };

  stage(0, 0);
  __syncthreads();              // drains vmcnt: buffer 0 ready
  int cur = 0;
  for (int ch = 0; ch < nchunk; ++ch){
    bool more = (ch + 1 < nchunk);
    if (more) stage(cur ^ 1, ch + 1);   // DMA in flight during the FMA phase
    // row fragments from LDS (rows r0..r0+31 are columns; uniform-addr broadcast)
    float4 rv0[4], rv1[4];
    #pragma unroll
    for (int j = 0; j < 4; ++j){
      rv0[j] = *(const float4*)&Xc[cur][0][(r0 + w*4 + j)*4];
      rv1[j] = *(const float4*)&Xc[cur][1][(r0 + w*4 + j)*4];
    }
    #pragma unroll
    for (int q = 0; q < 16; ++q){
      float4 cv0 = *(const float4*)&Xc[cur][0][(q*64 + lane)*4];
      float4 cv1 = *(const float4*)&Xc[cur][1][(q*64 + lane)*4];
      #pragma unroll
      for (int j = 0; j < 4; ++j){
        float s = acc[j][q];   // strict sequential col order: bitwise-stable result
        s = fmaf(rv0[j].x, cv0.x, s); s = fmaf(rv0[j].y, cv0.y, s);
        s = fmaf(rv0[j].z, cv0.z, s); s = fmaf(rv0[j].w, cv0.w, s);
        s = fmaf(rv1[j].x, cv1.x, s); s = fmaf(rv1[j].y, cv1.y, s);
        s = fmaf(rv1[j].z, cv1.z, s); s = fmaf(rv1[j].w, cv1.w, s);
        acc[j][q] = s;
      }
    }
    if (more){
      __syncthreads();   // all waves done reading cur; my ch+1 DMA drained (had
      cur ^= 1;          // the full FMA phase to land) -> idle buf ready
    }
  }
  // transform to negdist = 2*dot - xx_r - xx_m, then to sortable uints
  float xxm[16];
  #pragma unroll
  for (int q = 0; q < 16; ++q) xxm[q] = xx[b*ND + q*64 + lane];
  unsigned uk[4][16];
  #pragma unroll
  for (int j = 0; j < 4; ++j){
    float xr = xx[b*ND + r0 + w*4 + j];
    #pragma unroll
    for (int q = 0; q < 16; ++q){
      float f = 2.f*acc[j][q] - xr - xxm[q];
      unsigned bv = __float_as_uint(f);
      uk[j][q] = (bv & 0x80000000u) ? ~bv : (bv | 0x80000000u);  // order-preserving
    }
  }
  // radix binary search for T = 20th-largest key per row (bit 31: only the diagonal
  // reaches it, count==1<20 always -> skip). Early exit at exact count==20 (set-equal).
  unsigned pref[4] = {0u, 0u, 0u, 0u};
  unsigned done = 0u;
  #pragma unroll 1
  for (int bit = 30; bit >= 0; --bit){
    #pragma unroll
    for (int u = 0; u < 4; ++u){
      if (done & (1u << u)) continue;           // wave-uniform (ballot-derived)
      unsigned cand = pref[u] | (1u << bit);
      int c = 0;
      #pragma unroll
      for (int q = 0; q < 16; ++q)
        c += (int)__popcll(__ballot(uk[u][q] >= cand));
      if (c >= KNN){
        pref[u] = cand;
        if (c == KNN) done |= (1u << u);
      }
    }
    if (done == 15u) break;
  }
  // emit: all keys > T, plus lowest-global-index keys == T to fill to 20
  unsigned long long mlt = (1ull << lane) - 1ull;   // lanes below me
  #pragma unroll
  for (int u = 0; u < 4; ++u){
    unsigned T = pref[u];
    int cg = 0;
    #pragma unroll
    for (int q = 0; q < 16; ++q) cg += (int)__popcll(__ballot(uk[u][q] > T));
    int need_eq = KNN - cg;                          // >= 1 by construction
    int* op = &idxp[((size_t)(b*ND + r0 + w*4 + u))*KNN];
    int run_gt = 0, run_eq = 0;
    #pragma unroll
    for (int q = 0; q < 16; ++q){
      unsigned k = uk[u][q];
      unsigned long long bg = __ballot(k > T);
      unsigned long long be = __ballot(k == T);
      if (k > T) op[run_gt + (int)__popcll(bg & mlt)] = q*64 + lane;
      if (k == T){
        int r = run_eq + (int)__popcll(be & mlt);
        if (r < need_eq) op[cg + r] = q*64 + lane;
      }
      run_gt += (int)__popcll(bg);
      run_eq += (int)__popcll(be);
    }
  }
}

// ------ phase A (register-blocked), tiled x, 16 batches (grid 512 = 2 blocks/CU) -----
template<int O>
__global__ __launch_bounds__(256) void k_phaseA(const float* __restrict__ x,
    const float* __restrict__ W, const float* __restrict__ bias,
    const float* __restrict__ gamma, const float* __restrict__ beta,
    float* __restrict__ zs, float* __restrict__ ccv, int C, int XS){
  constexpr int TO = O/16;
  constexpr int WP = O + 4;
  __shared__ float W1s[32*WP];
  __shared__ float dWs[32*WP];
  __shared__ float Xs[32*33];
  int blk = blockIdx.x;
  int b = blk & 15, n0 = (blk >> 4)*32;
  int t = threadIdx.x;
  int ot = t & 15, nt = t >> 4;
  int obase = ot*TO;
  int nl = nt*2;
  float az[TO][2] = {}, ac[TO][2] = {};
  for (int cc = 0; cc < C; cc += 32){
    int KC = (C - cc < 32) ? (C - cc) : 32;
    int NG = (KC + 3) >> 2;
    for (int i = t; i < O*KC; i += 256){
      int o = i % O, c = i / O;
      float w1 = W[(size_t)o*2*C + cc + c];
      float w2 = W[(size_t)o*2*C + C + cc + c];
      W1s[c*WP + o] = w1;
      dWs[c*WP + o] = w2 - w1;
    }
    for (int i = t; i < 32*NG; i += 256){
      int row = i & 31, g = i >> 5;
      float4 v = *(const float4*)&x[(size_t)(b*XS + cc + g*4)*ND + (size_t)(n0+row)*4];
      Xs[(g*4+0)*33 + row] = v.x;
      Xs[(g*4+1)*33 + row] = v.y;
      Xs[(g*4+2)*33 + row] = v.z;
      Xs[(g*4+3)*33 + row] = v.w;
    }
    __syncthreads();
    for (int c = 0; c < KC; ++c){
      float xv0 = Xs[c*33 + nl];
      float xv1 = Xs[c*33 + nl + 1];
      #pragma unroll
      for (int i = 0; i < TO; ++i){
        float w1 = W1s[c*WP + obase + i];
        float dw = dWs[c*WP + obase + i];
        az[i][0] = fmaf(w1, xv0, az[i][0]);
        az[i][1] = fmaf(w1, xv1, az[i][1]);
        ac[i][0] = fmaf(dw, xv0, ac[i][0]);
        ac[i][1] = fmaf(dw, xv1, ac[i][1]);
      }
    }
    __syncthreads();
  }
  #pragma unroll
  for (int i = 0; i < TO; ++i){
    int o = obase + i;
    float alpha = gamma[o]*BNSC;
    float bb = bias[o], be = beta[o];
    #pragma unroll
    for (int q = 0; q < 2; ++q){
      int n = n0 + nl + q;
      size_t off = ((size_t)b*ND + n)*O + o;
      zs[off]  = az[i][q]*alpha;
      ccv[off] = fmaf(ac[i][q] + bb, alpha, be);
    }
  }
}

// ------ phase B: out = max_k leaky(zs[idx_k]+cc); TILED knn-layout writes ------------
template<bool DOXX, bool TILED>
__global__ __launch_bounds__(256) void k_phaseB(const float* __restrict__ zs,
    const float* __restrict__ ccv, const int* __restrict__ idxp,
    float* __restrict__ outp, float* __restrict__ xxout,
    int O, int ostride, int ooff){
  int t = threadIdx.x;
  int lane = t & 63, w = t >> 6;
  int b = blockIdx.x & 15;
  int n = (blockIdx.x >> 4)*4 + w;
  int gn = (b << 10) + n;
  int mm[KNN];
  const int* ip = idxp + (size_t)gn*KNN;
  #pragma unroll
  for (int k = 0; k < KNN; ++k) mm[k] = ip[k];
  float sq = 0.f;
  for (int o = lane; o < O; o += 64){
    float cvv = ccv[(size_t)gn*O + o];
    float mx = -INFINITY;
    #pragma unroll 4
    for (int k = 0; k < KNN; ++k){
      float v = leakyf(zs[((size_t)(b*ND) + mm[k])*O + o] + cvv);
      mx = fmaxf(mx, v);
    }
    if (TILED)
      outp[(size_t)(b*O + (o & ~3))*ND + (size_t)n*4 + (o & 3)] = mx;
    else
      outp[(size_t)gn*ostride + ooff + o] = mx;
    if (DOXX) sq = fmaf(mx, mx, sq);
  }
  if (DOXX){
    #pragma unroll
    for (int off = 32; off; off >>= 1) sq += __shfl_down(sq, off);
    if (lane == 0) xxout[gn] = sq;
  }
}

// --------- qkv: LDS-tiled GEMM [16K x 64] @ [64 x 192] + bias (r13 proven) -----------
__global__ __launch_bounds__(256) void k_lin(const float* __restrict__ in,
    const float* __restrict__ Wm, const float* __restrict__ bias,
    float* __restrict__ outp){
  __shared__ float Ws[64*196];    // 50.2 KB: Ws[c*196 + o]
  __shared__ float Xs[64*33];     // 8.4 KB:  Xs[c*33 + row]
  int blk = blockIdx.x;
  int b = blk & 15, n0 = (blk >> 4)*32;
  int bn0 = (b << 10) + n0;
  int t = threadIdx.x;
  int ot = t & 15, nt = t >> 4;
  int obase = ot*12;
  int nl = nt*2;
  // stage W transposed: coalesced global read Wm[o*64+c] (i contiguous)
  for (int i = t; i < 192*64; i += 256){
    int c = i & 63, o = i >> 6;
    Ws[c*196 + o] = Wm[i];
  }
  // stage A-tile: coalesced float4 rows -> Xs[c][row]
  for (int i = t; i < 32*16; i += 256){
    int row = i >> 4, c4 = i & 15;
    float4 v = *(const float4*)&in[((size_t)(bn0 + row))*64 + c4*4];
    Xs[(c4*4+0)*33 + row] = v.x;
    Xs[(c4*4+1)*33 + row] = v.y;
    Xs[(c4*4+2)*33 + row] = v.z;
    Xs[(c4*4+3)*33 + row] = v.w;
  }
  __syncthreads();
  float acc[12][2];
  #pragma unroll
  for (int i = 0; i < 12; ++i){
    float bb = bias[obase + i];
    acc[i][0] = bb; acc[i][1] = bb;     // bias first, then c ascending == old order
  }
  for (int c = 0; c < 64; ++c){
    float xv0 = Xs[c*33 + nl];
    float xv1 = Xs[c*33 + nl + 1];
    #pragma unroll
    for (int i = 0; i < 12; ++i){
      float wv = Ws[c*196 + obase + i];
      acc[i][0] = fmaf(wv, xv0, acc[i][0]);
      acc[i][1] = fmaf(wv, xv1, acc[i][1]);
    }
  }
  #pragma unroll
  for (int q = 0; q < 2; ++q){
    float* op = &outp[(size_t)(bn0 + nl + q)*192 + obase];
    #pragma unroll
    for (int v4 = 0; v4 < 3; ++v4)
      *(float4*)&op[v4*4] = make_float4(acc[v4*4+0][q], acc[v4*4+1][q],
                                        acc[v4*4+2][q], acc[v4*4+3][q]);
  }
}

// ------- flash-decode attention (no-max exp): 2 heads/block ---------------------------
__global__ __launch_bounds__(256, 1) void k_attn_part(const float* __restrict__ qkv,
    float* __restrict__ pl, float* __restrict__ pacc){
  __shared__ __align__(16) float Ks[2][KPS*8];
  __shared__ __align__(16) float Vs[2][KPS*8];
  int blk = blockIdx.x;                // b(16, low bits) x ksl(8) x hp(4) = 512 blocks
  int b = blk & 15; int ksl = (blk >> 4) & 7; int hp = blk >> 7;
  int t = threadIdx.x;
  int hh = t >> 7;                     // wave-uniform head select within pair
  int h = hp*2 + hh;
  int lq = t & 127;
  for (int i = t; i < 2*KPS*8; i += 256){
    int hi = (i >= KPS*8) ? 1 : 0;
    int r = i - hi*KPS*8;
    int m = r >> 3, dd = r & 7;
    size_t base = ((size_t)b*ND + ksl*KPS + m)*192 + (hp*2 + hi)*8 + dd;
    Ks[hi][r] = qkv[base + 64];
    Vs[hi][r] = qkv[base + 128];
  }
  __syncthreads();
  const float scale = 0.35355339059327373f;
  float q[8][8];
  #pragma unroll
  for (int u = 0; u < 8; ++u){
    int n = u*128 + lq;
    const float4* qp = (const float4*)(qkv + ((size_t)b*ND + n)*192 + h*8);
    float4 q0 = qp[0], q1 = qp[1];
    q[u][0]=q0.x*scale; q[u][1]=q0.y*scale; q[u][2]=q0.z*scale; q[u][3]=q0.w*scale;
    q[u][4]=q1.x*scale; q[u][5]=q1.y*scale; q[u][6]=q1.z*scale; q[u][7]=q1.w*scale;
  }
  float l[8] = {};
  float acc[8][8] = {};
  for (int m = 0; m < KPS; ++m){
    float4 k0 = *(const float4*)&Ks[hh][m*8];
    float4 k1 = *(const float4*)&Ks[hh][m*8+4];
    float4 v0 = *(const float4*)&Vs[hh][m*8];
    float4 v1 = *(const float4*)&Vs[hh][m*8+4];
    #pragma unroll
    for (int u = 0; u < 8; ++u){
      float s;
      s = q[u][0]*k0.x;           s = fmaf(q[u][1], k0.y, s);
      s = fmaf(q[u][2], k0.z, s); s = fmaf(q[u][3], k0.w, s);
      s = fmaf(q[u][4], k1.x, s); s = fmaf(q[u][5], k1.y, s);
      s = fmaf(q[u][6], k1.z, s); s = fmaf(q[u][7], k1.w, s);
      float p = __expf(s);        // scores tiny: exp-without-max is safe; merge = sum
      l[u] += p;
      acc[u][0] = fmaf(p, v0.x, acc[u][0]);
      acc[u][1] = fmaf(p, v0.y, acc[u][1]);
      acc[u][2] = fmaf(p, v0.z, acc[u][2]);
      acc[u][3] = fmaf(p, v0.w, acc[u][3]);
      acc[u][4] = fmaf(p, v1.x, acc[u][4]);
      acc[u][5] = fmaf(p, v1.y, acc[u][5]);
      acc[u][6] = fmaf(p, v1.z, acc[u][6]);
      acc[u][7] = fmaf(p, v1.w, acc[u][7]);
    }
  }
  #pragma unroll
  for (int u = 0; u < 8; ++u){
    int n = u*128 + lq;
    size_t pidx = (((size_t)(b*8 + h))*8 + ksl)*ND + n;
    pl[pidx] = l[u];
    float4* ap = (float4*)&pacc[pidx*8];
    ap[0] = make_float4(acc[u][0], acc[u][1], acc[u][2], acc[u][3]);
    ap[1] = make_float4(acc[u][4], acc[u][5], acc[u][6], acc[u][7]);
  }
}

// ------- flash-decode combine: plain sums --------------------------------------------
__global__ __launch_bounds__(256) void k_attn_comb(const float* __restrict__ pl,
    const float* __restrict__ pacc, float* __restrict__ attno){
  int b = blockIdx.x & 15;
  int inner = (blockIdx.x >> 4)*256 + threadIdx.x;   // 0..8191 = h(8) x n(1024)
  int h = inner >> 10; int n = inner & 1023;
  int bh = b*8 + h;
  float L = 0.f;
  float o[8] = {};
  #pragma unroll
  for (int s = 0; s < KSL; ++s){
    size_t pidx = ((size_t)bh*8 + s)*ND + n;
    L += pl[pidx];
    const float4* ap = (const float4*)&pacc[pidx*8];
    float4 a0 = ap[0], a1 = ap[1];
    o[0] += a0.x; o[1] += a0.y; o[2] += a0.z; o[3] += a0.w;
    o[4] += a1.x; o[5] += a1.y; o[6] += a1.z; o[7] += a1.w;
  }
  float inv = 1.f/L;
  float4* dst = (float4*)&attno[((size_t)b*ND + n)*64 + h*8];
  dst[0] = make_float4(o[0]*inv, o[1]*inv, o[2]*inv, o[3]*inv);
  dst[1] = make_float4(o[4]*inv, o[5]*inv, o[6]*inv, o[7]*inv);
}

// ------- out-proj + pair-mean: emb[bn,f] = 0.5*(proj[2f]+proj[2f+1]) -----------------
__global__ __launch_bounds__(256) void k_projmean(const float* __restrict__ attno,
    const float* __restrict__ Wo, const float* __restrict__ bo,
    float* __restrict__ emb){
  int b = blockIdx.x & 15;
  int inner = (blockIdx.x >> 4)*256 + threadIdx.x;   // 0..32767 = n(1024) x f(32)
  int n = inner >> 5; int f = inner & 31;
  int bn = (b << 10) + n;
  const float4* ip = (const float4*)(attno + (size_t)bn*64);
  int o0 = 2*f, o1 = 2*f + 1;
  const float4* w0 = (const float4*)(Wo + (size_t)o0*64);
  const float4* w1 = (const float4*)(Wo + (size_t)o1*64);
  float s0 = bo[o0], s1 = bo[o1];
  #pragma unroll
  for (int c = 0; c < 16; ++c){
    float4 a = ip[c], u = w0[c], v = w1[c];
    s0 = fmaf(a.x,u.x,s0); s0 = fmaf(a.y,u.y,s0); s0 = fmaf(a.z,u.z,s0); s0 = fmaf(a.w,u.w,s0);
    s1 = fmaf(a.x,v.x,s1); s1 = fmaf(a.y,v.y,s1); s1 = fmaf(a.z,v.z,s1); s1 = fmaf(a.w,v.w,s1);
  }
  emb[(size_t)bn*32 + f] = 0.5f*(s0 + s1);
}

// ---------------- fused attention pool: one block per b16 ----------------------------
// sout base = out+8; b16*ND+n == br*(8*ND)+b8*ND+n (branch output slices contiguous)
__global__ __launch_bounds__(256) void k_poolfuse(const float* __restrict__ emb,
    const float* __restrict__ attw, float* __restrict__ sout,
    float* __restrict__ pooled){
  __shared__ float part[8][32];
  __shared__ float meanv[32];
  __shared__ float gv[32];
  __shared__ float sc[ND];
  int b = blockIdx.x, t = threadIdx.x;
  int f = t & 31, j = t >> 5;
  const float* eb = emb + (size_t)b*ND*32;
  float s = 0.f;
  for (int n = j; n < ND; n += 8) s += eb[n*32 + f];
  part[j][f] = s;
  __syncthreads();
  if (t < 32){
    float m = 0.f;
    for (int j2 = 0; j2 < 8; ++j2) m += part[j2][t];
    meanv[t] = m * (1.f/ND);
  }
  __syncthreads();
  if (t < 32){
    float acc = 0.f;
    for (int f2 = 0; f2 < 32; ++f2) acc = fmaf(meanv[f2], attw[f2*32 + t], acc);
    gv[t] = tanhf(acc);
  }
  __syncthreads();
  for (int n = t; n < ND; n += 256){
    const float4* ep = (const float4*)(eb + n*32);
    float acc = 0.f;
    #pragma unroll
    for (int f4 = 0; f4 < 8; ++f4){
      float4 e = ep[f4];
      acc = fmaf(e.x, gv[f4*4+0], acc);
      acc = fmaf(e.y, gv[f4*4+1], acc);
      acc = fmaf(e.z, gv[f4*4+2], acc);
      acc = fmaf(e.w, gv[f4*4+3], acc);
    }
    float sg = 1.f/(1.f + __expf(-acc));
    sout[(size_t)b*ND + n] = sg;
    sc[n] = sg;
  }
  __syncthreads();
  float pacc = 0.f;
  for (int n = j; n < ND; n += 8) pacc = fmaf(eb[n*32 + f], sc[n], pacc);
  part[j][f] = pacc;
  __syncthreads();
  if (t < 32){
    float m = 0.f;
    for (int j2 = 0; j2 < 8; ++j2) m += part[j2][t];
    pooled[b*32 + t] = m;
  }
}

// ---------------- NTN head: LDS-staged weights (2-phase, 32KB each) ------------------
__global__ __launch_bounds__(256) void k_head(const float* __restrict__ p1,
    const float* __restrict__ p2, const float* __restrict__ ntnw,
    const float* __restrict__ ntnv, const float* __restrict__ ntnb,
    const float* __restrict__ fc1w, const float* __restrict__ fc1b,
    const float* __restrict__ scw, const float* __restrict__ scb,
    float* __restrict__ outscore){
  __shared__ __align__(16) float Wl[8192];
  __shared__ float Vl[512];
  __shared__ float F1[256];
  __shared__ float ds[8][32];
  __shared__ float tv[8][16];
  __shared__ float hv[8][16];
  int t = threadIdx.x;
  {
    int b = t >> 5, f = t & 31;
    ds[b][f] = p1[b*32+f] - p2[b*32+f];
  }
  for (int i = t; i < 512; i += 256) Vl[i] = ntnv[i];
  if (t < 256) F1[t] = fc1w[t];
  float acc = 0.f;
  for (int ph = 0; ph < 2; ++ph){
    __syncthreads();
    {
      const float4* src = (const float4*)(ntnw + ph*8192);
      float4* dst = (float4*)Wl;
      for (int i = t; i < 2048; i += 256) dst[i] = src[i];
    }
    __syncthreads();
    if (t < 128){
      int b = t >> 4, tt = t & 15;
      for (int fi = 0; fi < 16; ++fi){
        float df = ds[b][ph*16 + fi];
        #pragma unroll 8
        for (int gg = 0; gg < 32; ++gg)
          acc = fmaf(df*ds[b][gg], Wl[(fi*32+gg)*16 + tt], acc);
      }
    }
  }
  if (t < 128){
    int b = t >> 4, tt = t & 15;
    acc += ntnb[tt];
    for (int gg = 0; gg < 32; ++gg) acc = fmaf(ds[b][gg], Vl[tt*32+gg], acc);
    tv[b][tt] = fmaxf(acc, 0.f);
  }
  __syncthreads();
  if (t < 128){
    int b = t >> 4, i = t & 15;
    float a2 = fc1b[i];
    for (int kk = 0; kk < 16; ++kk) a2 = fmaf(tv[b][kk], F1[i*16+kk], a2);
    hv[b][i] = fmaxf(a2, 0.f);
  }
  __syncthreads();
  if (t < 8){
    float a3 = scb[0];
    for (int i = 0; i < 16; ++i) a3 = fmaf(hv[t][i], scw[i], a3);
    outscore[t] = 1.f/(1.f + __expf(-a3));
  }
}

// =====================================================================================
extern "C" void kernel_launch(void* const* d_in, const int* in_sizes, int n_in,
                              void* d_out, int out_size, void* d_ws, size_t ws_size,
                              hipStream_t stream) {
  auto F = [&](int i){ return (const float*)d_in[i]; };
  const float* f1 = F(0); const float* f2 = F(1);
  const float* cw[3] = { F(2), F(6), F(10) };
  const float* cb[3] = { F(3), F(7), F(11) };
  const float* cg[3] = { F(4), F(8), F(12) };
  const float* cB[3] = { F(5), F(9), F(13) };
  const float* sw[3] = { F(14), F(18), F(22) };
  const float* sb[3] = { F(15), F(19), F(23) };
  const float* sg[3] = { F(16), F(20), F(24) };
  const float* sB[3] = { F(17), F(21), F(25) };
  const float* mha_wi = F(26); const float* mha_bi = F(27);
  const float* mha_wo = F(28); const float* mha_bo = F(29);
  const float* att_w  = F(30);
  const float* ntn_w  = F(31); const float* ntn_v = F(32); const float* ntn_b = F(33);
  const float* fc1_w  = F(34); const float* fc1_b = F(35);
  const float* sc_w   = F(36); const float* sc_b  = F(37);
  float* out = (float*)d_out;

  char* ws = (char*)d_ws;
  const size_t MB = 1 << 20;
  // Edge-conv segment [0, 35MB) -- dead before the MHA phase begins:
  float* xA   = (float*)(ws + 0*MB);        // 8 MB  (16 x 1024 x 128 x 4)
  float* xB   = (float*)(ws + 8*MB);        // 8 MB
  float* zs   = (float*)(ws + 16*MB);       // 8 MB
  float* cvb  = (float*)(ws + 24*MB);       // 8 MB
  int*   idxb = (int*)  (ws + 32*MB);       // 1.25 MB
  float* xxb  = (float*)(ws + 34*MB);       // 64 KB
  float* fuse = (float*)(ws + 35*MB);       // 4 MB  [dies after k_lin]
  // MHA segment aliases the dead edge-conv buffers (stream-sequential, safe):
  float* qkv   = (float*)(ws + 0*MB);       // 12 MB over xA + xB-low   (dead)
  float* plb   = (float*)(ws + 12*MB);      // 4 MB  over xB-high       (dead)
  float* paccb = (float*)(ws + 16*MB);      // 32 MB over zs,cvb,idx,xx,fuse (dead)
  float* attno = (float*)(ws + 48*MB);      // 4 MB fresh
  float* emb   = (float*)(ws + 52*MB);      // 2 MB fresh
  float* pooled= (float*)(ws + 54*MB);      // 2 KB
  (void)ws_size;

  auto knn = [&](const float* xin, int CS, int nch8){
    k_knn<<<BD*32, 512, 0, stream>>>(xin, xxb, idxb, CS, nch8);
  };
  auto phA = [&](const float* xin, int C, int XS, int O, const float* W, const float* bb,
                 const float* gg, const float* be){
    if (O == 64)       k_phaseA<64> <<<BD*32, 256, 0, stream>>>(xin, W, bb, gg, be, zs, cvb, C, XS);
    else if (O == 128) k_phaseA<128><<<BD*32, 256, 0, stream>>>(xin, W, bb, gg, be, zs, cvb, C, XS);
    else               k_phaseA<32> <<<BD*32, 256, 0, stream>>>(xin, W, bb, gg, be, zs, cvb, C, XS);
  };

  for (int part = 0; part < 2; ++part){
    const float* const* Wl = part ? sw : cw;
    const float* const* bl = part ? sb : cb;
    const float* const* gl = part ? sg : cg;
    const float* const* Bl = part ? sB : cB;
    int C0 = part ? 12 : 3;
    int CS0 = part ? 12 : 4;
    // layer 0: C0 -> 64 (both branches at once: 16 batches)
    if (part) k_prep<12,12><<<BD*ND/256, 256, 0, stream>>>(f1, f2, xA, xxb, 3);
    else      k_prep<3, 4> <<<BD*ND/256, 256, 0, stream>>>(f1, f2, xA, xxb, 0);
    knn(xA, CS0, part ? 2 : 1);
    phA(xA, C0, CS0, 64, Wl[0], bl[0], gl[0], Bl[0]);
    k_phaseB<true,true><<<BD*ND/4, 256, 0, stream>>>(zs, cvb, idxb, xB, xxb, 64, 0, 0);
    // layer 1: 64 -> 128 (xx produced by phaseB)
    knn(xB, 64, 8);
    phA(xB, 64, 64, 128, Wl[1], bl[1], gl[1], Bl[1]);
    k_phaseB<true,true><<<BD*ND/4, 256, 0, stream>>>(zs, cvb, idxb, xA, xxb, 128, 0, 0);
    // layer 2: 128 -> 32, written into fuse at column offset (row-major)
    knn(xA, 128, 16);
    phA(xA, 128, 128, 32, Wl[2], bl[2], gl[2], Bl[2]);
    k_phaseB<false,false><<<BD*ND/4, 256, 0, stream>>>(zs, cvb, idxb, fuse, nullptr, 32, 64, part*32);
  }
  // MHA (flash-decode, no-max exp) over all 16 batches
  k_lin<<<BD*32, 256, 0, stream>>>(fuse, mha_wi, mha_bi, qkv);
  k_attn_part<<<BD*4*KSL, 256, 0, stream>>>(qkv, plb, paccb);
  k_attn_comb<<<(BD*8*ND)/256, 256, 0, stream>>>(plb, paccb, attno);
  k_projmean<<<(BD*ND*32)/256, 256, 0, stream>>>(attno, mha_wo, mha_bo, emb);
  // fused attention pool (sout slices are contiguous across the 16 batches)
  k_poolfuse<<<BD, 256, 0, stream>>>(emb, att_w, out + 8, pooled);
  k_head<<<1, 256, 0, stream>>>(pooled, pooled + 256, ntn_w, ntn_v, ntn_b,
                                fc1_w, fc1_b, sc_w, sc_b, out);
}

// Round 16
// 1031.677 us; speedup vs baseline: 1.1829x; 1.0038x over previous
//
#include <hip/hip_runtime.h>
#include <math.h>

#define BD 16      // fused batches: 2 branches x 8
#define ND 1024
#define KNN 20
#define NEGS 0.2f
#define BNSC 0.99999500003749969482f
#define KSL 8      // key slices for flash-decode attention
#define KPS 128    // keys per slice

__device__ __forceinline__ float leakyf(float y){ return y >= 0.f ? y : NEGS*y; }

// async global->LDS DMA, 16B per lane: dest = wave-uniform base + lane*16 (HW rule),
// src = per-lane. With the tiled x layout the src is lane-CONTIGUOUS (1KB/instr).
__device__ __forceinline__ void gl_lds16(const float* g, float* l){
  __builtin_amdgcn_global_load_lds(
      (const __attribute__((address_space(1))) void*)g,
      (__attribute__((address_space(3))) void*)l, 16, 0, 0);
}

// r16: knn reverted to the r13 optimum (4 waves x 4 rows, DMA ping-pong, 115us) --
// r14 (8 rows/wave) and r15 (8 waves/block) both regressed; the 4x4 shape is the
// measured structural floor. New: k_attn_comb + k_projmean fused into k_combproj
// (attno 4MB intermediate eliminated; 32-row tile lives in 8.7KB LDS; identical
// accumulation order in both phases -> bitwise-identical).

// -------- fused input slice + transpose + xx: tiled write, both branches -------------
template<int C, int CS>
__global__ __launch_bounds__(256) void k_prep(const float* __restrict__ f1,
                                              const float* __restrict__ f2,
                                              float* __restrict__ x,
                                              float* __restrict__ xx, int c0){
  int blk = blockIdx.x;
  int b = blk & 15;
  int n = (blk >> 4)*256 + threadIdx.x;
  const float* feat = (b & 8) ? f2 : f1;
  int b8 = b & 7;
  float v[CS];
  float s = 0.f;
  #pragma unroll
  for (int c = 0; c < C; ++c){
    v[c] = feat[((size_t)(b8*15) + c0 + c)*ND + n];
    s = fmaf(v[c], v[c], s);
  }
  #pragma unroll
  for (int c = C; c < CS; ++c) v[c] = 0.f;
  #pragma unroll
  for (int g = 0; g < CS/4; ++g)
    *(float4*)&x[(size_t)(b*CS + g*4)*ND + (size_t)n*4] =
        make_float4(v[g*4], v[g*4+1], v[g*4+2], v[g*4+3]);
  xx[b*ND + n] = s;
}

// -------- fused gram + exact top-20: DMA ping-pong staging (r13 proven, 115us) -------
__global__ __launch_bounds__(256)
void k_knn(const float* __restrict__ x,
    const float* __restrict__ xx, int* __restrict__ idxp, int CS, int nchunk){
  __shared__ __align__(16) float Xc[2][2][4096];   // [buf][quad-array][1024*4] = 64KB
  int b = blockIdx.x & 15;
  int r0 = (blockIdx.x >> 4)*16;
  int t = threadIdx.x;
  int lane = t & 63;
  int w = __builtin_amdgcn_readfirstlane(t >> 6);   // wave-uniform wave id
  const float* xb = x + (size_t)b*ND*CS;            // tiled [G][n][4]
  float acc[4][16];
  #pragma unroll
  for (int j = 0; j < 4; ++j)
    #pragma unroll
    for (int q = 0; q < 16; ++q) acc[j][q] = 0.f;

  // stage chunk ch (quads 2ch, 2ch+1) into buffer buf via DMA; zero-fill padded quads
  auto stage = [&](int buf, int ch){
    int g0 = 2*ch, g1 = 2*ch + 1;
    bool v1 = (g1*4 < CS);                       // g0 always valid by construction
    #pragma unroll
    for (int i = 0; i < 4; ++i){
      int m = i*256 + t;
      unsigned ub = (unsigned)((i*256 + (w << 6))*4);   // wave-uniform elem base
      gl_lds16(&xb[((size_t)g0*ND + m)*4], &Xc[buf][0][ub]);
      if (v1) gl_lds16(&xb[((size_t)g1*ND + m)*4], &Xc[buf][1][ub]);
      else    *(float4*)&Xc[buf][1][m*4] = make_float4(0.f,0.f,0.f,0.f);
    }
  };

  stage(0, 0);
  __syncthreads();              // drains vmcnt: buffer 0 ready
  int cur = 0;
  for (int ch = 0; ch < nchunk; ++ch){
    bool more = (ch + 1 < nchunk);
    if (more) stage(cur ^ 1, ch + 1);   // DMA in flight during the FMA phase
    // row fragments from LDS (rows r0..r0+15 are columns; uniform-addr broadcast)
    float4 rv0[4], rv1[4];
    #pragma unroll
    for (int j = 0; j < 4; ++j){
      rv0[j] = *(const float4*)&Xc[cur][0][(r0 + w*4 + j)*4];
      rv1[j] = *(const float4*)&Xc[cur][1][(r0 + w*4 + j)*4];
    }
    #pragma unroll
    for (int q = 0; q < 16; ++q){
      float4 cv0 = *(const float4*)&Xc[cur][0][(q*64 + lane)*4];
      float4 cv1 = *(const float4*)&Xc[cur][1][(q*64 + lane)*4];
      #pragma unroll
      for (int j = 0; j < 4; ++j){
        float s = acc[j][q];   // strict sequential col order: bitwise-stable result
        s = fmaf(rv0[j].x, cv0.x, s); s = fmaf(rv0[j].y, cv0.y, s);
        s = fmaf(rv0[j].z, cv0.z, s); s = fmaf(rv0[j].w, cv0.w, s);
        s = fmaf(rv1[j].x, cv1.x, s); s = fmaf(rv1[j].y, cv1.y, s);
        s = fmaf(rv1[j].z, cv1.z, s); s = fmaf(rv1[j].w, cv1.w, s);
        acc[j][q] = s;
      }
    }
    if (more){
      __syncthreads();   // all waves done reading cur; my ch+1 DMA drained (had
      cur ^= 1;          // the full FMA phase to land) -> idle buf ready
    }
  }
  // transform to negdist = 2*dot - xx_r - xx_m, then to sortable uints
  float xxm[16];
  #pragma unroll
  for (int q = 0; q < 16; ++q) xxm[q] = xx[b*ND + q*64 + lane];
  unsigned uk[4][16];
  #pragma unroll
  for (int j = 0; j < 4; ++j){
    float xr = xx[b*ND + r0 + w*4 + j];
    #pragma unroll
    for (int q = 0; q < 16; ++q){
      float f = 2.f*acc[j][q] - xr - xxm[q];
      unsigned bv = __float_as_uint(f);
      uk[j][q] = (bv & 0x80000000u) ? ~bv : (bv | 0x80000000u);  // order-preserving
    }
  }
  // radix binary search for T = 20th-largest key per row (bit 31: only the diagonal
  // reaches it, count==1<20 always -> skip). Early exit at exact count==20 (set-equal).
  unsigned pref[4] = {0u, 0u, 0u, 0u};
  unsigned done = 0u;
  #pragma unroll 1
  for (int bit = 30; bit >= 0; --bit){
    #pragma unroll
    for (int u = 0; u < 4; ++u){
      if (done & (1u << u)) continue;           // wave-uniform (ballot-derived)
      unsigned cand = pref[u] | (1u << bit);
      int c = 0;
      #pragma unroll
      for (int q = 0; q < 16; ++q)
        c += (int)__popcll(__ballot(uk[u][q] >= cand));
      if (c >= KNN){
        pref[u] = cand;
        if (c == KNN) done |= (1u << u);
      }
    }
    if (done == 15u) break;
  }
  // emit: all keys > T, plus lowest-global-index keys == T to fill to 20
  unsigned long long mlt = (1ull << lane) - 1ull;   // lanes below me
  #pragma unroll
  for (int u = 0; u < 4; ++u){
    unsigned T = pref[u];
    int cg = 0;
    #pragma unroll
    for (int q = 0; q < 16; ++q) cg += (int)__popcll(__ballot(uk[u][q] > T));
    int need_eq = KNN - cg;                          // >= 1 by construction
    int* op = &idxp[((size_t)(b*ND + r0 + w*4 + u))*KNN];
    int run_gt = 0, run_eq = 0;
    #pragma unroll
    for (int q = 0; q < 16; ++q){
      unsigned k = uk[u][q];
      unsigned long long bg = __ballot(k > T);
      unsigned long long be = __ballot(k == T);
      if (k > T) op[run_gt + (int)__popcll(bg & mlt)] = q*64 + lane;
      if (k == T){
        int r = run_eq + (int)__popcll(be & mlt);
        if (r < need_eq) op[cg + r] = q*64 + lane;
      }
      run_gt += (int)__popcll(bg);
      run_eq += (int)__popcll(be);
    }
  }
}

// ------ phase A (register-blocked), tiled x, 16 batches (grid 512 = 2 blocks/CU) -----
template<int O>
__global__ __launch_bounds__(256) void k_phaseA(const float* __restrict__ x,
    const float* __restrict__ W, const float* __restrict__ bias,
    const float* __restrict__ gamma, const float* __restrict__ beta,
    float* __restrict__ zs, float* __restrict__ ccv, int C, int XS){
  constexpr int TO = O/16;
  constexpr int WP = O + 4;
  __shared__ float W1s[32*WP];
  __shared__ float dWs[32*WP];
  __shared__ float Xs[32*33];
  int blk = blockIdx.x;
  int b = blk & 15, n0 = (blk >> 4)*32;
  int t = threadIdx.x;
  int ot = t & 15, nt = t >> 4;
  int obase = ot*TO;
  int nl = nt*2;
  float az[TO][2] = {}, ac[TO][2] = {};
  for (int cc = 0; cc < C; cc += 32){
    int KC = (C - cc < 32) ? (C - cc) : 32;
    int NG = (KC + 3) >> 2;
    for (int i = t; i < O*KC; i += 256){
      int o = i % O, c = i / O;
      float w1 = W[(size_t)o*2*C + cc + c];
      float w2 = W[(size_t)o*2*C + C + cc + c];
      W1s[c*WP + o] = w1;
      dWs[c*WP + o] = w2 - w1;
    }
    for (int i = t; i < 32*NG; i += 256){
      int row = i & 31, g = i >> 5;
      float4 v = *(const float4*)&x[(size_t)(b*XS + cc + g*4)*ND + (size_t)(n0+row)*4];
      Xs[(g*4+0)*33 + row] = v.x;
      Xs[(g*4+1)*33 + row] = v.y;
      Xs[(g*4+2)*33 + row] = v.z;
      Xs[(g*4+3)*33 + row] = v.w;
    }
    __syncthreads();
    for (int c = 0; c < KC; ++c){
      float xv0 = Xs[c*33 + nl];
      float xv1 = Xs[c*33 + nl + 1];
      #pragma unroll
      for (int i = 0; i < TO; ++i){
        float w1 = W1s[c*WP + obase + i];
        float dw = dWs[c*WP + obase + i];
        az[i][0] = fmaf(w1, xv0, az[i][0]);
        az[i][1] = fmaf(w1, xv1, az[i][1]);
        ac[i][0] = fmaf(dw, xv0, ac[i][0]);
        ac[i][1] = fmaf(dw, xv1, ac[i][1]);
      }
    }
    __syncthreads();
  }
  #pragma unroll
  for (int i = 0; i < TO; ++i){
    int o = obase + i;
    float alpha = gamma[o]*BNSC;
    float bb = bias[o], be = beta[o];
    #pragma unroll
    for (int q = 0; q < 2; ++q){
      int n = n0 + nl + q;
      size_t off = ((size_t)b*ND + n)*O + o;
      zs[off]  = az[i][q]*alpha;
      ccv[off] = fmaf(ac[i][q] + bb, alpha, be);
    }
  }
}

// ------ phase B: out = max_k leaky(zs[idx_k]+cc); TILED knn-layout writes ------------
template<bool DOXX, bool TILED>
__global__ __launch_bounds__(256) void k_phaseB(const float* __restrict__ zs,
    const float* __restrict__ ccv, const int* __restrict__ idxp,
    float* __restrict__ outp, float* __restrict__ xxout,
    int O, int ostride, int ooff){
  int t = threadIdx.x;
  int lane = t & 63, w = t >> 6;
  int b = blockIdx.x & 15;
  int n = (blockIdx.x >> 4)*4 + w;
  int gn = (b << 10) + n;
  int mm[KNN];
  const int* ip = idxp + (size_t)gn*KNN;
  #pragma unroll
  for (int k = 0; k < KNN; ++k) mm[k] = ip[k];
  float sq = 0.f;
  for (int o = lane; o < O; o += 64){
    float cvv = ccv[(size_t)gn*O + o];
    float mx = -INFINITY;
    #pragma unroll 4
    for (int k = 0; k < KNN; ++k){
      float v = leakyf(zs[((size_t)(b*ND) + mm[k])*O + o] + cvv);
      mx = fmaxf(mx, v);
    }
    if (TILED)
      outp[(size_t)(b*O + (o & ~3))*ND + (size_t)n*4 + (o & 3)] = mx;
    else
      outp[(size_t)gn*ostride + ooff + o] = mx;
    if (DOXX) sq = fmaf(mx, mx, sq);
  }
  if (DOXX){
    #pragma unroll
    for (int off = 32; off; off >>= 1) sq += __shfl_down(sq, off);
    if (lane == 0) xxout[gn] = sq;
  }
}

// --------- qkv: LDS-tiled GEMM [16K x 64] @ [64 x 192] + bias (r13 proven) -----------
__global__ __launch_bounds__(256) void k_lin(const float* __restrict__ in,
    const float* __restrict__ Wm, const float* __restrict__ bias,
    float* __restrict__ outp){
  __shared__ float Ws[64*196];    // 50.2 KB: Ws[c*196 + o]
  __shared__ float Xs[64*33];     // 8.4 KB:  Xs[c*33 + row]
  int blk = blockIdx.x;
  int b = blk & 15, n0 = (blk >> 4)*32;
  int bn0 = (b << 10) + n0;
  int t = threadIdx.x;
  int ot = t & 15, nt = t >> 4;
  int obase = ot*12;
  int nl = nt*2;
  // stage W transposed: coalesced global read Wm[o*64+c] (i contiguous)
  for (int i = t; i < 192*64; i += 256){
    int c = i & 63, o = i >> 6;
    Ws[c*196 + o] = Wm[i];
  }
  // stage A-tile: coalesced float4 rows -> Xs[c][row]
  for (int i = t; i < 32*16; i += 256){
    int row = i >> 4, c4 = i & 15;
    float4 v = *(const float4*)&in[((size_t)(bn0 + row))*64 + c4*4];
    Xs[(c4*4+0)*33 + row] = v.x;
    Xs[(c4*4+1)*33 + row] = v.y;
    Xs[(c4*4+2)*33 + row] = v.z;
    Xs[(c4*4+3)*33 + row] = v.w;
  }
  __syncthreads();
  float acc[12][2];
  #pragma unroll
  for (int i = 0; i < 12; ++i){
    float bb = bias[obase + i];
    acc[i][0] = bb; acc[i][1] = bb;     // bias first, then c ascending == old order
  }
  for (int c = 0; c < 64; ++c){
    float xv0 = Xs[c*33 + nl];
    float xv1 = Xs[c*33 + nl + 1];
    #pragma unroll
    for (int i = 0; i < 12; ++i){
      float wv = Ws[c*196 + obase + i];
      acc[i][0] = fmaf(wv, xv0, acc[i][0]);
      acc[i][1] = fmaf(wv, xv1, acc[i][1]);
    }
  }
  #pragma unroll
  for (int q = 0; q < 2; ++q){
    float* op = &outp[(size_t)(bn0 + nl + q)*192 + obase];
    #pragma unroll
    for (int v4 = 0; v4 < 3; ++v4)
      *(float4*)&op[v4*4] = make_float4(acc[v4*4+0][q], acc[v4*4+1][q],
                                        acc[v4*4+2][q], acc[v4*4+3][q]);
  }
}

// ------- flash-decode attention (no-max exp): 2 heads/block ---------------------------
__global__ __launch_bounds__(256, 1) void k_attn_part(const float* __restrict__ qkv,
    float* __restrict__ pl, float* __restrict__ pacc){
  __shared__ __align__(16) float Ks[2][KPS*8];
  __shared__ __align__(16) float Vs[2][KPS*8];
  int blk = blockIdx.x;                // b(16, low bits) x ksl(8) x hp(4) = 512 blocks
  int b = blk & 15; int ksl = (blk >> 4) & 7; int hp = blk >> 7;
  int t = threadIdx.x;
  int hh = t >> 7;                     // wave-uniform head select within pair
  int h = hp*2 + hh;
  int lq = t & 127;
  for (int i = t; i < 2*KPS*8; i += 256){
    int hi = (i >= KPS*8) ? 1 : 0;
    int r = i - hi*KPS*8;
    int m = r >> 3, dd = r & 7;
    size_t base = ((size_t)b*ND + ksl*KPS + m)*192 + (hp*2 + hi)*8 + dd;
    Ks[hi][r] = qkv[base + 64];
    Vs[hi][r] = qkv[base + 128];
  }
  __syncthreads();
  const float scale = 0.35355339059327373f;
  float q[8][8];
  #pragma unroll
  for (int u = 0; u < 8; ++u){
    int n = u*128 + lq;
    const float4* qp = (const float4*)(qkv + ((size_t)b*ND + n)*192 + h*8);
    float4 q0 = qp[0], q1 = qp[1];
    q[u][0]=q0.x*scale; q[u][1]=q0.y*scale; q[u][2]=q0.z*scale; q[u][3]=q0.w*scale;
    q[u][4]=q1.x*scale; q[u][5]=q1.y*scale; q[u][6]=q1.z*scale; q[u][7]=q1.w*scale;
  }
  float l[8] = {};
  float acc[8][8] = {};
  for (int m = 0; m < KPS; ++m){
    float4 k0 = *(const float4*)&Ks[hh][m*8];
    float4 k1 = *(const float4*)&Ks[hh][m*8+4];
    float4 v0 = *(const float4*)&Vs[hh][m*8];
    float4 v1 = *(const float4*)&Vs[hh][m*8+4];
    #pragma unroll
    for (int u = 0; u < 8; ++u){
      float s;
      s = q[u][0]*k0.x;           s = fmaf(q[u][1], k0.y, s);
      s = fmaf(q[u][2], k0.z, s); s = fmaf(q[u][3], k0.w, s);
      s = fmaf(q[u][4], k1.x, s); s = fmaf(q[u][5], k1.y, s);
      s = fmaf(q[u][6], k1.z, s); s = fmaf(q[u][7], k1.w, s);
      float p = __expf(s);        // scores tiny: exp-without-max is safe; merge = sum
      l[u] += p;
      acc[u][0] = fmaf(p, v0.x, acc[u][0]);
      acc[u][1] = fmaf(p, v0.y, acc[u][1]);
      acc[u][2] = fmaf(p, v0.z, acc[u][2]);
      acc[u][3] = fmaf(p, v0.w, acc[u][3]);
      acc[u][4] = fmaf(p, v1.x, acc[u][4]);
      acc[u][5] = fmaf(p, v1.y, acc[u][5]);
      acc[u][6] = fmaf(p, v1.z, acc[u][6]);
      acc[u][7] = fmaf(p, v1.w, acc[u][7]);
    }
  }
  #pragma unroll
  for (int u = 0; u < 8; ++u){
    int n = u*128 + lq;
    size_t pidx = (((size_t)(b*8 + h))*8 + ksl)*ND + n;
    pl[pidx] = l[u];
    float4* ap = (float4*)&pacc[pidx*8];
    ap[0] = make_float4(acc[u][0], acc[u][1], acc[u][2], acc[u][3]);
    ap[1] = make_float4(acc[u][4], acc[u][5], acc[u][6], acc[u][7]);
  }
}

// ------- fused flash-decode combine + out-proj + pair-mean ---------------------------
// Phase 1 (8 heads x 32 rows): exact k_attn_comb math -> att[row][64] in LDS.
// Phase 2 (32 f x 32 rows over 4 iters): exact k_projmean math from LDS (broadcast
// reads). Accumulation order identical to the two originals -> bitwise-identical.
// Eliminates the 4MB attno intermediate + one launch.
__global__ __launch_bounds__(256) void k_combproj(const float* __restrict__ pl,
    const float* __restrict__ pacc, const float* __restrict__ Wo,
    const float* __restrict__ bo, float* __restrict__ emb){
  __shared__ float att[32][68];
  int blk = blockIdx.x;
  int b = blk & 15, n0 = (blk >> 4)*32;
  int t = threadIdx.x;
  {
    int h = t >> 5, nl = t & 31;
    int n = n0 + nl;
    int bh = b*8 + h;
    float L = 0.f;
    float o[8] = {};
    #pragma unroll
    for (int s = 0; s < KSL; ++s){
      size_t pidx = ((size_t)bh*8 + s)*ND + n;
      L += pl[pidx];
      const float4* ap = (const float4*)&pacc[pidx*8];
      float4 a0 = ap[0], a1 = ap[1];
      o[0] += a0.x; o[1] += a0.y; o[2] += a0.z; o[3] += a0.w;
      o[4] += a1.x; o[5] += a1.y; o[6] += a1.z; o[7] += a1.w;
    }
    float inv = 1.f/L;
    #pragma unroll
    for (int d = 0; d < 8; ++d) att[nl][h*8 + d] = o[d]*inv;
  }
  __syncthreads();
  #pragma unroll
  for (int it = 0; it < 4; ++it){
    int idx = it*256 + t;
    int nl = idx >> 5, f = idx & 31;
    const float* arow = att[nl];
    int o0 = 2*f, o1 = 2*f + 1;
    const float4* w0 = (const float4*)(Wo + (size_t)o0*64);
    const float4* w1 = (const float4*)(Wo + (size_t)o1*64);
    float s0 = bo[o0], s1 = bo[o1];
    #pragma unroll
    for (int c = 0; c < 16; ++c){
      float4 a = *(const float4*)&arow[c*4];
      float4 u = w0[c], v = w1[c];
      s0 = fmaf(a.x,u.x,s0); s0 = fmaf(a.y,u.y,s0); s0 = fmaf(a.z,u.z,s0); s0 = fmaf(a.w,u.w,s0);
      s1 = fmaf(a.x,v.x,s1); s1 = fmaf(a.y,v.y,s1); s1 = fmaf(a.z,v.z,s1); s1 = fmaf(a.w,v.w,s1);
    }
    emb[(size_t)((b << 10) + n0 + nl)*32 + f] = 0.5f*(s0 + s1);
  }
}

// ---------------- fused attention pool: one block per b16 ----------------------------
// sout base = out+8; b16*ND+n == br*(8*ND)+b8*ND+n (branch output slices contiguous)
__global__ __launch_bounds__(256) void k_poolfuse(const float* __restrict__ emb,
    const float* __restrict__ attw, float* __restrict__ sout,
    float* __restrict__ pooled){
  __shared__ float part[8][32];
  __shared__ float meanv[32];
  __shared__ float gv[32];
  __shared__ float sc[ND];
  int b = blockIdx.x, t = threadIdx.x;
  int f = t & 31, j = t >> 5;
  const float* eb = emb + (size_t)b*ND*32;
  float s = 0.f;
  for (int n = j; n < ND; n += 8) s += eb[n*32 + f];
  part[j][f] = s;
  __syncthreads();
  if (t < 32){
    float m = 0.f;
    for (int j2 = 0; j2 < 8; ++j2) m += part[j2][t];
    meanv[t] = m * (1.f/ND);
  }
  __syncthreads();
  if (t < 32){
    float acc = 0.f;
    for (int f2 = 0; f2 < 32; ++f2) acc = fmaf(meanv[f2], attw[f2*32 + t], acc);
    gv[t] = tanhf(acc);
  }
  __syncthreads();
  for (int n = t; n < ND; n += 256){
    const float4* ep = (const float4*)(eb + n*32);
    float acc = 0.f;
    #pragma unroll
    for (int f4 = 0; f4 < 8; ++f4){
      float4 e = ep[f4];
      acc = fmaf(e.x, gv[f4*4+0], acc);
      acc = fmaf(e.y, gv[f4*4+1], acc);
      acc = fmaf(e.z, gv[f4*4+2], acc);
      acc = fmaf(e.w, gv[f4*4+3], acc);
    }
    float sg = 1.f/(1.f + __expf(-acc));
    sout[(size_t)b*ND + n] = sg;
    sc[n] = sg;
  }
  __syncthreads();
  float pacc = 0.f;
  for (int n = j; n < ND; n += 8) pacc = fmaf(eb[n*32 + f], sc[n], pacc);
  part[j][f] = pacc;
  __syncthreads();
  if (t < 32){
    float m = 0.f;
    for (int j2 = 0; j2 < 8; ++j2) m += part[j2][t];
    pooled[b*32 + t] = m;
  }
}

// ---------------- NTN head: LDS-staged weights (2-phase, 32KB each) ------------------
__global__ __launch_bounds__(256) void k_head(const float* __restrict__ p1,
    const float* __restrict__ p2, const float* __restrict__ ntnw,
    const float* __restrict__ ntnv, const float* __restrict__ ntnb,
    const float* __restrict__ fc1w, const float* __restrict__ fc1b,
    const float* __restrict__ scw, const float* __restrict__ scb,
    float* __restrict__ outscore){
  __shared__ __align__(16) float Wl[8192];
  __shared__ float Vl[512];
  __shared__ float F1[256];
  __shared__ float ds[8][32];
  __shared__ float tv[8][16];
  __shared__ float hv[8][16];
  int t = threadIdx.x;
  {
    int b = t >> 5, f = t & 31;
    ds[b][f] = p1[b*32+f] - p2[b*32+f];
  }
  for (int i = t; i < 512; i += 256) Vl[i] = ntnv[i];
  if (t < 256) F1[t] = fc1w[t];
  float acc = 0.f;
  for (int ph = 0; ph < 2; ++ph){
    __syncthreads();
    {
      const float4* src = (const float4*)(ntnw + ph*8192);
      float4* dst = (float4*)Wl;
      for (int i = t; i < 2048; i += 256) dst[i] = src[i];
    }
    __syncthreads();
    if (t < 128){
      int b = t >> 4, tt = t & 15;
      for (int fi = 0; fi < 16; ++fi){
        float df = ds[b][ph*16 + fi];
        #pragma unroll 8
        for (int gg = 0; gg < 32; ++gg)
          acc = fmaf(df*ds[b][gg], Wl[(fi*32+gg)*16 + tt], acc);
      }
    }
  }
  if (t < 128){
    int b = t >> 4, tt = t & 15;
    acc += ntnb[tt];
    for (int gg = 0; gg < 32; ++gg) acc = fmaf(ds[b][gg], Vl[tt*32+gg], acc);
    tv[b][tt] = fmaxf(acc, 0.f);
  }
  __syncthreads();
  if (t < 128){
    int b = t >> 4, i = t & 15;
    float a2 = fc1b[i];
    for (int kk = 0; kk < 16; ++kk) a2 = fmaf(tv[b][kk], F1[i*16+kk], a2);
    hv[b][i] = fmaxf(a2, 0.f);
  }
  __syncthreads();
  if (t < 8){
    float a3 = scb[0];
    for (int i = 0; i < 16; ++i) a3 = fmaf(hv[t][i], scw[i], a3);
    outscore[t] = 1.f/(1.f + __expf(-a3));
  }
}

// =====================================================================================
extern "C" void kernel_launch(void* const* d_in, const int* in_sizes, int n_in,
                              void* d_out, int out_size, void* d_ws, size_t ws_size,
                              hipStream_t stream) {
  auto F = [&](int i){ return (const float*)d_in[i]; };
  const float* f1 = F(0); const float* f2 = F(1);
  const float* cw[3] = { F(2), F(6), F(10) };
  const float* cb[3] = { F(3), F(7), F(11) };
  const float* cg[3] = { F(4), F(8), F(12) };
  const float* cB[3] = { F(5), F(9), F(13) };
  const float* sw[3] = { F(14), F(18), F(22) };
  const float* sb[3] = { F(15), F(19), F(23) };
  const float* sg[3] = { F(16), F(20), F(24) };
  const float* sB[3] = { F(17), F(21), F(25) };
  const float* mha_wi = F(26); const float* mha_bi = F(27);
  const float* mha_wo = F(28); const float* mha_bo = F(29);
  const float* att_w  = F(30);
  const float* ntn_w  = F(31); const float* ntn_v = F(32); const float* ntn_b = F(33);
  const float* fc1_w  = F(34); const float* fc1_b = F(35);
  const float* sc_w   = F(36); const float* sc_b  = F(37);
  float* out = (float*)d_out;

  char* ws = (char*)d_ws;
  const size_t MB = 1 << 20;
  // Edge-conv segment [0, 35MB) -- dead before the MHA phase begins:
  float* xA   = (float*)(ws + 0*MB);        // 8 MB  (16 x 1024 x 128 x 4)
  float* xB   = (float*)(ws + 8*MB);        // 8 MB
  float* zs   = (float*)(ws + 16*MB);       // 8 MB
  float* cvb  = (float*)(ws + 24*MB);       // 8 MB
  int*   idxb = (int*)  (ws + 32*MB);       // 1.25 MB
  float* xxb  = (float*)(ws + 34*MB);       // 64 KB
  float* fuse = (float*)(ws + 35*MB);       // 4 MB  [dies after k_lin]
  // MHA segment aliases the dead edge-conv buffers (stream-sequential, safe):
  float* qkv   = (float*)(ws + 0*MB);       // 12 MB over xA + xB-low   (dead)
  float* plb   = (float*)(ws + 12*MB);      // 4 MB  over xB-high       (dead)
  float* paccb = (float*)(ws + 16*MB);      // 32 MB over zs,cvb,idx,xx,fuse (dead)
  float* emb   = (float*)(ws + 52*MB);      // 2 MB fresh
  float* pooled= (float*)(ws + 54*MB);      // 2 KB
  (void)ws_size;

  auto knn = [&](const float* xin, int CS, int nch8){
    k_knn<<<BD*64, 256, 0, stream>>>(xin, xxb, idxb, CS, nch8);
  };
  auto phA = [&](const float* xin, int C, int XS, int O, const float* W, const float* bb,
                 const float* gg, const float* be){
    if (O == 64)       k_phaseA<64> <<<BD*32, 256, 0, stream>>>(xin, W, bb, gg, be, zs, cvb, C, XS);
    else if (O == 128) k_phaseA<128><<<BD*32, 256, 0, stream>>>(xin, W, bb, gg, be, zs, cvb, C, XS);
    else               k_phaseA<32> <<<BD*32, 256, 0, stream>>>(xin, W, bb, gg, be, zs, cvb, C, XS);
  };

  for (int part = 0; part < 2; ++part){
    const float* const* Wl = part ? sw : cw;
    const float* const* bl = part ? sb : cb;
    const float* const* gl = part ? sg : cg;
    const float* const* Bl = part ? sB : cB;
    int C0 = part ? 12 : 3;
    int CS0 = part ? 12 : 4;
    // layer 0: C0 -> 64 (both branches at once: 16 batches)
    if (part) k_prep<12,12><<<BD*ND/256, 256, 0, stream>>>(f1, f2, xA, xxb, 3);
    else      k_prep<3, 4> <<<BD*ND/256, 256, 0, stream>>>(f1, f2, xA, xxb, 0);
    knn(xA, CS0, part ? 2 : 1);
    phA(xA, C0, CS0, 64, Wl[0], bl[0], gl[0], Bl[0]);
    k_phaseB<true,true><<<BD*ND/4, 256, 0, stream>>>(zs, cvb, idxb, xB, xxb, 64, 0, 0);
    // layer 1: 64 -> 128 (xx produced by phaseB)
    knn(xB, 64, 8);
    phA(xB, 64, 64, 128, Wl[1], bl[1], gl[1], Bl[1]);
    k_phaseB<true,true><<<BD*ND/4, 256, 0, stream>>>(zs, cvb, idxb, xA, xxb, 128, 0, 0);
    // layer 2: 128 -> 32, written into fuse at column offset (row-major)
    knn(xA, 128, 16);
    phA(xA, 128, 128, 32, Wl[2], bl[2], gl[2], Bl[2]);
    k_phaseB<false,false><<<BD*ND/4, 256, 0, stream>>>(zs, cvb, idxb, fuse, nullptr, 32, 64, part*32);
  }
  // MHA (flash-decode, no-max exp) over all 16 batches
  k_lin<<<BD*32, 256, 0, stream>>>(fuse, mha_wi, mha_bi, qkv);
  k_attn_part<<<BD*4*KSL, 256, 0, stream>>>(qkv, plb, paccb);
  k_combproj<<<BD*32, 256, 0, stream>>>(plb, paccb, mha_wo, mha_bo, emb);
  // fused attention pool (sout slices are contiguous across the 16 batches)
  k_poolfuse<<<BD, 256, 0, stream>>>(emb, att_w, out + 8, pooled);
  k_head<<<1, 256, 0, stream>>>(pooled, pooled + 256, ntn_w, ntn_v, ntn_b,
                                fc1_w, fc1_b, sc_w, sc_b, out);
}

// Round 17
// 999.924 us; speedup vs baseline: 1.2204x; 1.0318x over previous
//
#include <hip/hip_runtime.h>
#include <math.h>

#define BD 16      // fused batches: 2 branches x 8
#define ND 1024
#define KNN 20
#define NEGS 0.2f
#define BNSC 0.99999500003749969482f
#define KSL 8      // key slices for flash-decode attention
#define KPS 128    // keys per slice

__device__ __forceinline__ float leakyf(float y){ return y >= 0.f ? y : NEGS*y; }

// async global->LDS DMA, 16B per lane: dest = wave-uniform base + lane*16 (HW rule),
// src = per-lane. With the tiled x layout the src is lane-CONTIGUOUS (1KB/instr).
__device__ __forceinline__ void gl_lds16(const float* g, float* l){
  __builtin_amdgcn_global_load_lds(
      (const __attribute__((address_space(1))) void*)g,
      (__attribute__((address_space(3))) void*)l, 16, 0, 0);
}

// r17 == r13 (measured optimum, 996us): 16-batch branch fusion + b-affinity (XCD L2
// locality, FETCH 16.7->2.2MB/branch) + tiled x layout + knn 4 waves x 4 rows with
// global_load_lds ping-pong (115us floor; r14 8-rows and r15 8-waves both regressed;
// r16 comb+proj fusion neutral-negative -> dropped) + LDS-tiled k_lin (114->~6us).

// -------- fused input slice + transpose + xx: tiled write, both branches -------------
template<int C, int CS>
__global__ __launch_bounds__(256) void k_prep(const float* __restrict__ f1,
                                              const float* __restrict__ f2,
                                              float* __restrict__ x,
                                              float* __restrict__ xx, int c0){
  int blk = blockIdx.x;
  int b = blk & 15;
  int n = (blk >> 4)*256 + threadIdx.x;
  const float* feat = (b & 8) ? f2 : f1;
  int b8 = b & 7;
  float v[CS];
  float s = 0.f;
  #pragma unroll
  for (int c = 0; c < C; ++c){
    v[c] = feat[((size_t)(b8*15) + c0 + c)*ND + n];
    s = fmaf(v[c], v[c], s);
  }
  #pragma unroll
  for (int c = C; c < CS; ++c) v[c] = 0.f;
  #pragma unroll
  for (int g = 0; g < CS/4; ++g)
    *(float4*)&x[(size_t)(b*CS + g*4)*ND + (size_t)n*4] =
        make_float4(v[g*4], v[g*4+1], v[g*4+2], v[g*4+3]);
  xx[b*ND + n] = s;
}

// -------- fused gram + exact top-20: DMA ping-pong staging (proven, 115us) -----------
__global__ __launch_bounds__(256)
void k_knn(const float* __restrict__ x,
    const float* __restrict__ xx, int* __restrict__ idxp, int CS, int nchunk){
  __shared__ __align__(16) float Xc[2][2][4096];   // [buf][quad-array][1024*4] = 64KB
  int b = blockIdx.x & 15;
  int r0 = (blockIdx.x >> 4)*16;
  int t = threadIdx.x;
  int lane = t & 63;
  int w = __builtin_amdgcn_readfirstlane(t >> 6);   // wave-uniform wave id
  const float* xb = x + (size_t)b*ND*CS;            // tiled [G][n][4]
  float acc[4][16];
  #pragma unroll
  for (int j = 0; j < 4; ++j)
    #pragma unroll
    for (int q = 0; q < 16; ++q) acc[j][q] = 0.f;

  // stage chunk ch (quads 2ch, 2ch+1) into buffer buf via DMA; zero-fill padded quads
  auto stage = [&](int buf, int ch){
    int g0 = 2*ch, g1 = 2*ch + 1;
    bool v1 = (g1*4 < CS);                       // g0 always valid by construction
    #pragma unroll
    for (int i = 0; i < 4; ++i){
      int m = i*256 + t;
      unsigned ub = (unsigned)((i*256 + (w << 6))*4);   // wave-uniform elem base
      gl_lds16(&xb[((size_t)g0*ND + m)*4], &Xc[buf][0][ub]);
      if (v1) gl_lds16(&xb[((size_t)g1*ND + m)*4], &Xc[buf][1][ub]);
      else    *(float4*)&Xc[buf][1][m*4] = make_float4(0.f,0.f,0.f,0.f);
    }
  };

  stage(0, 0);
  __syncthreads();              // drains vmcnt: buffer 0 ready
  int cur = 0;
  for (int ch = 0; ch < nchunk; ++ch){
    bool more = (ch + 1 < nchunk);
    if (more) stage(cur ^ 1, ch + 1);   // DMA in flight during the FMA phase
    // row fragments from LDS (rows r0..r0+15 are columns; uniform-addr broadcast)
    float4 rv0[4], rv1[4];
    #pragma unroll
    for (int j = 0; j < 4; ++j){
      rv0[j] = *(const float4*)&Xc[cur][0][(r0 + w*4 + j)*4];
      rv1[j] = *(const float4*)&Xc[cur][1][(r0 + w*4 + j)*4];
    }
    #pragma unroll
    for (int q = 0; q < 16; ++q){
      float4 cv0 = *(const float4*)&Xc[cur][0][(q*64 + lane)*4];
      float4 cv1 = *(const float4*)&Xc[cur][1][(q*64 + lane)*4];
      #pragma unroll
      for (int j = 0; j < 4; ++j){
        float s = acc[j][q];   // strict sequential col order: bitwise-stable result
        s = fmaf(rv0[j].x, cv0.x, s); s = fmaf(rv0[j].y, cv0.y, s);
        s = fmaf(rv0[j].z, cv0.z, s); s = fmaf(rv0[j].w, cv0.w, s);
        s = fmaf(rv1[j].x, cv1.x, s); s = fmaf(rv1[j].y, cv1.y, s);
        s = fmaf(rv1[j].z, cv1.z, s); s = fmaf(rv1[j].w, cv1.w, s);
        acc[j][q] = s;
      }
    }
    if (more){
      __syncthreads();   // all waves done reading cur; my ch+1 DMA drained (had
      cur ^= 1;          // the full FMA phase to land) -> idle buf ready
    }
  }
  // transform to negdist = 2*dot - xx_r - xx_m, then to sortable uints
  float xxm[16];
  #pragma unroll
  for (int q = 0; q < 16; ++q) xxm[q] = xx[b*ND + q*64 + lane];
  unsigned uk[4][16];
  #pragma unroll
  for (int j = 0; j < 4; ++j){
    float xr = xx[b*ND + r0 + w*4 + j];
    #pragma unroll
    for (int q = 0; q < 16; ++q){
      float f = 2.f*acc[j][q] - xr - xxm[q];
      unsigned bv = __float_as_uint(f);
      uk[j][q] = (bv & 0x80000000u) ? ~bv : (bv | 0x80000000u);  // order-preserving
    }
  }
  // radix binary search for T = 20th-largest key per row (bit 31: only the diagonal
  // reaches it, count==1<20 always -> skip). Early exit at exact count==20 (set-equal).
  unsigned pref[4] = {0u, 0u, 0u, 0u};
  unsigned done = 0u;
  #pragma unroll 1
  for (int bit = 30; bit >= 0; --bit){
    #pragma unroll
    for (int u = 0; u < 4; ++u){
      if (done & (1u << u)) continue;           // wave-uniform (ballot-derived)
      unsigned cand = pref[u] | (1u << bit);
      int c = 0;
      #pragma unroll
      for (int q = 0; q < 16; ++q)
        c += (int)__popcll(__ballot(uk[u][q] >= cand));
      if (c >= KNN){
        pref[u] = cand;
        if (c == KNN) done |= (1u << u);
      }
    }
    if (done == 15u) break;
  }
  // emit: all keys > T, plus lowest-global-index keys == T to fill to 20
  unsigned long long mlt = (1ull << lane) - 1ull;   // lanes below me
  #pragma unroll
  for (int u = 0; u < 4; ++u){
    unsigned T = pref[u];
    int cg = 0;
    #pragma unroll
    for (int q = 0; q < 16; ++q) cg += (int)__popcll(__ballot(uk[u][q] > T));
    int need_eq = KNN - cg;                          // >= 1 by construction
    int* op = &idxp[((size_t)(b*ND + r0 + w*4 + u))*KNN];
    int run_gt = 0, run_eq = 0;
    #pragma unroll
    for (int q = 0; q < 16; ++q){
      unsigned k = uk[u][q];
      unsigned long long bg = __ballot(k > T);
      unsigned long long be = __ballot(k == T);
      if (k > T) op[run_gt + (int)__popcll(bg & mlt)] = q*64 + lane;
      if (k == T){
        int r = run_eq + (int)__popcll(be & mlt);
        if (r < need_eq) op[cg + r] = q*64 + lane;
      }
      run_gt += (int)__popcll(bg);
      run_eq += (int)__popcll(be);
    }
  }
}

// ------ phase A (register-blocked), tiled x, 16 batches (grid 512 = 2 blocks/CU) -----
template<int O>
__global__ __launch_bounds__(256) void k_phaseA(const float* __restrict__ x,
    const float* __restrict__ W, const float* __restrict__ bias,
    const float* __restrict__ gamma, const float* __restrict__ beta,
    float* __restrict__ zs, float* __restrict__ ccv, int C, int XS){
  constexpr int TO = O/16;
  constexpr int WP = O + 4;
  __shared__ float W1s[32*WP];
  __shared__ float dWs[32*WP];
  __shared__ float Xs[32*33];
  int blk = blockIdx.x;
  int b = blk & 15, n0 = (blk >> 4)*32;
  int t = threadIdx.x;
  int ot = t & 15, nt = t >> 4;
  int obase = ot*TO;
  int nl = nt*2;
  float az[TO][2] = {}, ac[TO][2] = {};
  for (int cc = 0; cc < C; cc += 32){
    int KC = (C - cc < 32) ? (C - cc) : 32;
    int NG = (KC + 3) >> 2;
    for (int i = t; i < O*KC; i += 256){
      int o = i % O, c = i / O;
      float w1 = W[(size_t)o*2*C + cc + c];
      float w2 = W[(size_t)o*2*C + C + cc + c];
      W1s[c*WP + o] = w1;
      dWs[c*WP + o] = w2 - w1;
    }
    for (int i = t; i < 32*NG; i += 256){
      int row = i & 31, g = i >> 5;
      float4 v = *(const float4*)&x[(size_t)(b*XS + cc + g*4)*ND + (size_t)(n0+row)*4];
      Xs[(g*4+0)*33 + row] = v.x;
      Xs[(g*4+1)*33 + row] = v.y;
      Xs[(g*4+2)*33 + row] = v.z;
      Xs[(g*4+3)*33 + row] = v.w;
    }
    __syncthreads();
    for (int c = 0; c < KC; ++c){
      float xv0 = Xs[c*33 + nl];
      float xv1 = Xs[c*33 + nl + 1];
      #pragma unroll
      for (int i = 0; i < TO; ++i){
        float w1 = W1s[c*WP + obase + i];
        float dw = dWs[c*WP + obase + i];
        az[i][0] = fmaf(w1, xv0, az[i][0]);
        az[i][1] = fmaf(w1, xv1, az[i][1]);
        ac[i][0] = fmaf(dw, xv0, ac[i][0]);
        ac[i][1] = fmaf(dw, xv1, ac[i][1]);
      }
    }
    __syncthreads();
  }
  #pragma unroll
  for (int i = 0; i < TO; ++i){
    int o = obase + i;
    float alpha = gamma[o]*BNSC;
    float bb = bias[o], be = beta[o];
    #pragma unroll
    for (int q = 0; q < 2; ++q){
      int n = n0 + nl + q;
      size_t off = ((size_t)b*ND + n)*O + o;
      zs[off]  = az[i][q]*alpha;
      ccv[off] = fmaf(ac[i][q] + bb, alpha, be);
    }
  }
}

// ------ phase B: out = max_k leaky(zs[idx_k]+cc); TILED knn-layout writes ------------
template<bool DOXX, bool TILED>
__global__ __launch_bounds__(256) void k_phaseB(const float* __restrict__ zs,
    const float* __restrict__ ccv, const int* __restrict__ idxp,
    float* __restrict__ outp, float* __restrict__ xxout,
    int O, int ostride, int ooff){
  int t = threadIdx.x;
  int lane = t & 63, w = t >> 6;
  int b = blockIdx.x & 15;
  int n = (blockIdx.x >> 4)*4 + w;
  int gn = (b << 10) + n;
  int mm[KNN];
  const int* ip = idxp + (size_t)gn*KNN;
  #pragma unroll
  for (int k = 0; k < KNN; ++k) mm[k] = ip[k];
  float sq = 0.f;
  for (int o = lane; o < O; o += 64){
    float cvv = ccv[(size_t)gn*O + o];
    float mx = -INFINITY;
    #pragma unroll 4
    for (int k = 0; k < KNN; ++k){
      float v = leakyf(zs[((size_t)(b*ND) + mm[k])*O + o] + cvv);
      mx = fmaxf(mx, v);
    }
    if (TILED)
      outp[(size_t)(b*O + (o & ~3))*ND + (size_t)n*4 + (o & 3)] = mx;
    else
      outp[(size_t)gn*ostride + ooff + o] = mx;
    if (DOXX) sq = fmaf(mx, mx, sq);
  }
  if (DOXX){
    #pragma unroll
    for (int off = 32; off; off >>= 1) sq += __shfl_down(sq, off);
    if (lane == 0) xxout[gn] = sq;
  }
}

// --------- qkv: LDS-tiled GEMM [16K x 64] @ [64 x 192] + bias ------------------------
__global__ __launch_bounds__(256) void k_lin(const float* __restrict__ in,
    const float* __restrict__ Wm, const float* __restrict__ bias,
    float* __restrict__ outp){
  __shared__ float Ws[64*196];    // 50.2 KB: Ws[c*196 + o]
  __shared__ float Xs[64*33];     // 8.4 KB:  Xs[c*33 + row]
  int blk = blockIdx.x;
  int b = blk & 15, n0 = (blk >> 4)*32;
  int bn0 = (b << 10) + n0;
  int t = threadIdx.x;
  int ot = t & 15, nt = t >> 4;
  int obase = ot*12;
  int nl = nt*2;
  // stage W transposed: coalesced global read Wm[o*64+c] (i contiguous)
  for (int i = t; i < 192*64; i += 256){
    int c = i & 63, o = i >> 6;
    Ws[c*196 + o] = Wm[i];
  }
  // stage A-tile: coalesced float4 rows -> Xs[c][row]
  for (int i = t; i < 32*16; i += 256){
    int row = i >> 4, c4 = i & 15;
    float4 v = *(const float4*)&in[((size_t)(bn0 + row))*64 + c4*4];
    Xs[(c4*4+0)*33 + row] = v.x;
    Xs[(c4*4+1)*33 + row] = v.y;
    Xs[(c4*4+2)*33 + row] = v.z;
    Xs[(c4*4+3)*33 + row] = v.w;
  }
  __syncthreads();
  float acc[12][2];
  #pragma unroll
  for (int i = 0; i < 12; ++i){
    float bb = bias[obase + i];
    acc[i][0] = bb; acc[i][1] = bb;     // bias first, then c ascending == old order
  }
  for (int c = 0; c < 64; ++c){
    float xv0 = Xs[c*33 + nl];
    float xv1 = Xs[c*33 + nl + 1];
    #pragma unroll
    for (int i = 0; i < 12; ++i){
      float wv = Ws[c*196 + obase + i];
      acc[i][0] = fmaf(wv, xv0, acc[i][0]);
      acc[i][1] = fmaf(wv, xv1, acc[i][1]);
    }
  }
  #pragma unroll
  for (int q = 0; q < 2; ++q){
    float* op = &outp[(size_t)(bn0 + nl + q)*192 + obase];
    #pragma unroll
    for (int v4 = 0; v4 < 3; ++v4)
      *(float4*)&op[v4*4] = make_float4(acc[v4*4+0][q], acc[v4*4+1][q],
                                        acc[v4*4+2][q], acc[v4*4+3][q]);
  }
}

// ------- flash-decode attention (no-max exp): 2 heads/block ---------------------------
__global__ __launch_bounds__(256, 1) void k_attn_part(const float* __restrict__ qkv,
    float* __restrict__ pl, float* __restrict__ pacc){
  __shared__ __align__(16) float Ks[2][KPS*8];
  __shared__ __align__(16) float Vs[2][KPS*8];
  int blk = blockIdx.x;                // b(16, low bits) x ksl(8) x hp(4) = 512 blocks
  int b = blk & 15; int ksl = (blk >> 4) & 7; int hp = blk >> 7;
  int t = threadIdx.x;
  int hh = t >> 7;                     // wave-uniform head select within pair
  int h = hp*2 + hh;
  int lq = t & 127;
  for (int i = t; i < 2*KPS*8; i += 256){
    int hi = (i >= KPS*8) ? 1 : 0;
    int r = i - hi*KPS*8;
    int m = r >> 3, dd = r & 7;
    size_t base = ((size_t)b*ND + ksl*KPS + m)*192 + (hp*2 + hi)*8 + dd;
    Ks[hi][r] = qkv[base + 64];
    Vs[hi][r] = qkv[base + 128];
  }
  __syncthreads();
  const float scale = 0.35355339059327373f;
  float q[8][8];
  #pragma unroll
  for (int u = 0; u < 8; ++u){
    int n = u*128 + lq;
    const float4* qp = (const float4*)(qkv + ((size_t)b*ND + n)*192 + h*8);
    float4 q0 = qp[0], q1 = qp[1];
    q[u][0]=q0.x*scale; q[u][1]=q0.y*scale; q[u][2]=q0.z*scale; q[u][3]=q0.w*scale;
    q[u][4]=q1.x*scale; q[u][5]=q1.y*scale; q[u][6]=q1.z*scale; q[u][7]=q1.w*scale;
  }
  float l[8] = {};
  float acc[8][8] = {};
  for (int m = 0; m < KPS; ++m){
    float4 k0 = *(const float4*)&Ks[hh][m*8];
    float4 k1 = *(const float4*)&Ks[hh][m*8+4];
    float4 v0 = *(const float4*)&Vs[hh][m*8];
    float4 v1 = *(const float4*)&Vs[hh][m*8+4];
    #pragma unroll
    for (int u = 0; u < 8; ++u){
      float s;
      s = q[u][0]*k0.x;           s = fmaf(q[u][1], k0.y, s);
      s = fmaf(q[u][2], k0.z, s); s = fmaf(q[u][3], k0.w, s);
      s = fmaf(q[u][4], k1.x, s); s = fmaf(q[u][5], k1.y, s);
      s = fmaf(q[u][6], k1.z, s); s = fmaf(q[u][7], k1.w, s);
      float p = __expf(s);        // scores tiny: exp-without-max is safe; merge = sum
      l[u] += p;
      acc[u][0] = fmaf(p, v0.x, acc[u][0]);
      acc[u][1] = fmaf(p, v0.y, acc[u][1]);
      acc[u][2] = fmaf(p, v0.z, acc[u][2]);
      acc[u][3] = fmaf(p, v0.w, acc[u][3]);
      acc[u][4] = fmaf(p, v1.x, acc[u][4]);
      acc[u][5] = fmaf(p, v1.y, acc[u][5]);
      acc[u][6] = fmaf(p, v1.z, acc[u][6]);
      acc[u][7] = fmaf(p, v1.w, acc[u][7]);
    }
  }
  #pragma unroll
  for (int u = 0; u < 8; ++u){
    int n = u*128 + lq;
    size_t pidx = (((size_t)(b*8 + h))*8 + ksl)*ND + n;
    pl[pidx] = l[u];
    float4* ap = (float4*)&pacc[pidx*8];
    ap[0] = make_float4(acc[u][0], acc[u][1], acc[u][2], acc[u][3]);
    ap[1] = make_float4(acc[u][4], acc[u][5], acc[u][6], acc[u][7]);
  }
}

// ------- flash-decode combine: plain sums --------------------------------------------
__global__ __launch_bounds__(256) void k_attn_comb(const float* __restrict__ pl,
    const float* __restrict__ pacc, float* __restrict__ attno){
  int b = blockIdx.x & 15;
  int inner = (blockIdx.x >> 4)*256 + threadIdx.x;   // 0..8191 = h(8) x n(1024)
  int h = inner >> 10; int n = inner & 1023;
  int bh = b*8 + h;
  float L = 0.f;
  float o[8] = {};
  #pragma unroll
  for (int s = 0; s < KSL; ++s){
    size_t pidx = ((size_t)bh*8 + s)*ND + n;
    L += pl[pidx];
    const float4* ap = (const float4*)&pacc[pidx*8];
    float4 a0 = ap[0], a1 = ap[1];
    o[0] += a0.x; o[1] += a0.y; o[2] += a0.z; o[3] += a0.w;
    o[4] += a1.x; o[5] += a1.y; o[6] += a1.z; o[7] += a1.w;
  }
  float inv = 1.f/L;
  float4* dst = (float4*)&attno[((size_t)b*ND + n)*64 + h*8];
  dst[0] = make_float4(o[0]*inv, o[1]*inv, o[2]*inv, o[3]*inv);
  dst[1] = make_float4(o[4]*inv, o[5]*inv, o[6]*inv, o[7]*inv);
}

// ------- out-proj + pair-mean: emb[bn,f] = 0.5*(proj[2f]+proj[2f+1]) -----------------
__global__ __launch_bounds__(256) void k_projmean(const float* __restrict__ attno,
    const float* __restrict__ Wo, const float* __restrict__ bo,
    float* __restrict__ emb){
  int b = blockIdx.x & 15;
  int inner = (blockIdx.x >> 4)*256 + threadIdx.x;   // 0..32767 = n(1024) x f(32)
  int n = inner >> 5; int f = inner & 31;
  int bn = (b << 10) + n;
  const float4* ip = (const float4*)(attno + (size_t)bn*64);
  int o0 = 2*f, o1 = 2*f + 1;
  const float4* w0 = (const float4*)(Wo + (size_t)o0*64);
  const float4* w1 = (const float4*)(Wo + (size_t)o1*64);
  float s0 = bo[o0], s1 = bo[o1];
  #pragma unroll
  for (int c = 0; c < 16; ++c){
    float4 a = ip[c], u = w0[c], v = w1[c];
    s0 = fmaf(a.x,u.x,s0); s0 = fmaf(a.y,u.y,s0); s0 = fmaf(a.z,u.z,s0); s0 = fmaf(a.w,u.w,s0);
    s1 = fmaf(a.x,v.x,s1); s1 = fmaf(a.y,v.y,s1); s1 = fmaf(a.z,v.z,s1); s1 = fmaf(a.w,v.w,s1);
  }
  emb[(size_t)bn*32 + f] = 0.5f*(s0 + s1);
}

// ---------------- fused attention pool: one block per b16 ----------------------------
// sout base = out+8; b16*ND+n == br*(8*ND)+b8*ND+n (branch output slices contiguous)
__global__ __launch_bounds__(256) void k_poolfuse(const float* __restrict__ emb,
    const float* __restrict__ attw, float* __restrict__ sout,
    float* __restrict__ pooled){
  __shared__ float part[8][32];
  __shared__ float meanv[32];
  __shared__ float gv[32];
  __shared__ float sc[ND];
  int b = blockIdx.x, t = threadIdx.x;
  int f = t & 31, j = t >> 5;
  const float* eb = emb + (size_t)b*ND*32;
  float s = 0.f;
  for (int n = j; n < ND; n += 8) s += eb[n*32 + f];
  part[j][f] = s;
  __syncthreads();
  if (t < 32){
    float m = 0.f;
    for (int j2 = 0; j2 < 8; ++j2) m += part[j2][t];
    meanv[t] = m * (1.f/ND);
  }
  __syncthreads();
  if (t < 32){
    float acc = 0.f;
    for (int f2 = 0; f2 < 32; ++f2) acc = fmaf(meanv[f2], attw[f2*32 + t], acc);
    gv[t] = tanhf(acc);
  }
  __syncthreads();
  for (int n = t; n < ND; n += 256){
    const float4* ep = (const float4*)(eb + n*32);
    float acc = 0.f;
    #pragma unroll
    for (int f4 = 0; f4 < 8; ++f4){
      float4 e = ep[f4];
      acc = fmaf(e.x, gv[f4*4+0], acc);
      acc = fmaf(e.y, gv[f4*4+1], acc);
      acc = fmaf(e.z, gv[f4*4+2], acc);
      acc = fmaf(e.w, gv[f4*4+3], acc);
    }
    float sg = 1.f/(1.f + __expf(-acc));
    sout[(size_t)b*ND + n] = sg;
    sc[n] = sg;
  }
  __syncthreads();
  float pacc = 0.f;
  for (int n = j; n < ND; n += 8) pacc = fmaf(eb[n*32 + f], sc[n], pacc);
  part[j][f] = pacc;
  __syncthreads();
  if (t < 32){
    float m = 0.f;
    for (int j2 = 0; j2 < 8; ++j2) m += part[j2][t];
    pooled[b*32 + t] = m;
  }
}

// ---------------- NTN head: LDS-staged weights (2-phase, 32KB each) ------------------
__global__ __launch_bounds__(256) void k_head(const float* __restrict__ p1,
    const float* __restrict__ p2, const float* __restrict__ ntnw,
    const float* __restrict__ ntnv, const float* __restrict__ ntnb,
    const float* __restrict__ fc1w, const float* __restrict__ fc1b,
    const float* __restrict__ scw, const float* __restrict__ scb,
    float* __restrict__ outscore){
  __shared__ __align__(16) float Wl[8192];
  __shared__ float Vl[512];
  __shared__ float F1[256];
  __shared__ float ds[8][32];
  __shared__ float tv[8][16];
  __shared__ float hv[8][16];
  int t = threadIdx.x;
  {
    int b = t >> 5, f = t & 31;
    ds[b][f] = p1[b*32+f] - p2[b*32+f];
  }
  for (int i = t; i < 512; i += 256) Vl[i] = ntnv[i];
  if (t < 256) F1[t] = fc1w[t];
  float acc = 0.f;
  for (int ph = 0; ph < 2; ++ph){
    __syncthreads();
    {
      const float4* src = (const float4*)(ntnw + ph*8192);
      float4* dst = (float4*)Wl;
      for (int i = t; i < 2048; i += 256) dst[i] = src[i];
    }
    __syncthreads();
    if (t < 128){
      int b = t >> 4, tt = t & 15;
      for (int fi = 0; fi < 16; ++fi){
        float df = ds[b][ph*16 + fi];
        #pragma unroll 8
        for (int gg = 0; gg < 32; ++gg)
          acc = fmaf(df*ds[b][gg], Wl[(fi*32+gg)*16 + tt], acc);
      }
    }
  }
  if (t < 128){
    int b = t >> 4, tt = t & 15;
    acc += ntnb[tt];
    for (int gg = 0; gg < 32; ++gg) acc = fmaf(ds[b][gg], Vl[tt*32+gg], acc);
    tv[b][tt] = fmaxf(acc, 0.f);
  }
  __syncthreads();
  if (t < 128){
    int b = t >> 4, i = t & 15;
    float a2 = fc1b[i];
    for (int kk = 0; kk < 16; ++kk) a2 = fmaf(tv[b][kk], F1[i*16+kk], a2);
    hv[b][i] = fmaxf(a2, 0.f);
  }
  __syncthreads();
  if (t < 8){
    float a3 = scb[0];
    for (int i = 0; i < 16; ++i) a3 = fmaf(hv[t][i], scw[i], a3);
    outscore[t] = 1.f/(1.f + __expf(-a3));
  }
}

// =====================================================================================
extern "C" void kernel_launch(void* const* d_in, const int* in_sizes, int n_in,
                              void* d_out, int out_size, void* d_ws, size_t ws_size,
                              hipStream_t stream) {
  auto F = [&](int i){ return (const float*)d_in[i]; };
  const float* f1 = F(0); const float* f2 = F(1);
  const float* cw[3] = { F(2), F(6), F(10) };
  const float* cb[3] = { F(3), F(7), F(11) };
  const float* cg[3] = { F(4), F(8), F(12) };
  const float* cB[3] = { F(5), F(9), F(13) };
  const float* sw[3] = { F(14), F(18), F(22) };
  const float* sb[3] = { F(15), F(19), F(23) };
  const float* sg[3] = { F(16), F(20), F(24) };
  const float* sB[3] = { F(17), F(21), F(25) };
  const float* mha_wi = F(26); const float* mha_bi = F(27);
  const float* mha_wo = F(28); const float* mha_bo = F(29);
  const float* att_w  = F(30);
  const float* ntn_w  = F(31); const float* ntn_v = F(32); const float* ntn_b = F(33);
  const float* fc1_w  = F(34); const float* fc1_b = F(35);
  const float* sc_w   = F(36); const float* sc_b  = F(37);
  float* out = (float*)d_out;

  char* ws = (char*)d_ws;
  const size_t MB = 1 << 20;
  // Edge-conv segment [0, 35MB) -- dead before the MHA phase begins:
  float* xA   = (float*)(ws + 0*MB);        // 8 MB  (16 x 1024 x 128 x 4)
  float* xB   = (float*)(ws + 8*MB);        // 8 MB
  float* zs   = (float*)(ws + 16*MB);       // 8 MB
  float* cvb  = (float*)(ws + 24*MB);       // 8 MB
  int*   idxb = (int*)  (ws + 32*MB);       // 1.25 MB
  float* xxb  = (float*)(ws + 34*MB);       // 64 KB
  float* fuse = (float*)(ws + 35*MB);       // 4 MB  [dies after k_lin]
  // MHA segment aliases the dead edge-conv buffers (stream-sequential, safe):
  float* qkv   = (float*)(ws + 0*MB);       // 12 MB over xA + xB-low   (dead)
  float* plb   = (float*)(ws + 12*MB);      // 4 MB  over xB-high       (dead)
  float* paccb = (float*)(ws + 16*MB);      // 32 MB over zs,cvb,idx,xx,fuse (dead)
  float* attno = (float*)(ws + 48*MB);      // 4 MB fresh
  float* emb   = (float*)(ws + 52*MB);      // 2 MB fresh
  float* pooled= (float*)(ws + 54*MB);      // 2 KB
  (void)ws_size;

  auto knn = [&](const float* xin, int CS, int nch8){
    k_knn<<<BD*64, 256, 0, stream>>>(xin, xxb, idxb, CS, nch8);
  };
  auto phA = [&](const float* xin, int C, int XS, int O, const float* W, const float* bb,
                 const float* gg, const float* be){
    if (O == 64)       k_phaseA<64> <<<BD*32, 256, 0, stream>>>(xin, W, bb, gg, be, zs, cvb, C, XS);
    else if (O == 128) k_phaseA<128><<<BD*32, 256, 0, stream>>>(xin, W, bb, gg, be, zs, cvb, C, XS);
    else               k_phaseA<32> <<<BD*32, 256, 0, stream>>>(xin, W, bb, gg, be, zs, cvb, C, XS);
  };

  for (int part = 0; part < 2; ++part){
    const float* const* Wl = part ? sw : cw;
    const float* const* bl = part ? sb : cb;
    const float* const* gl = part ? sg : cg;
    const float* const* Bl = part ? sB : cB;
    int C0 = part ? 12 : 3;
    int CS0 = part ? 12 : 4;
    // layer 0: C0 -> 64 (both branches at once: 16 batches)
    if (part) k_prep<12,12><<<BD*ND/256, 256, 0, stream>>>(f1, f2, xA, xxb, 3);
    else      k_prep<3, 4> <<<BD*ND/256, 256, 0, stream>>>(f1, f2, xA, xxb, 0);
    knn(xA, CS0, part ? 2 : 1);
    phA(xA, C0, CS0, 64, Wl[0], bl[0], gl[0], Bl[0]);
    k_phaseB<true,true><<<BD*ND/4, 256, 0, stream>>>(zs, cvb, idxb, xB, xxb, 64, 0, 0);
    // layer 1: 64 -> 128 (xx produced by phaseB)
    knn(xB, 64, 8);
    phA(xB, 64, 64, 128, Wl[1], bl[1], gl[1], Bl[1]);
    k_phaseB<true,true><<<BD*ND/4, 256, 0, stream>>>(zs, cvb, idxb, xA, xxb, 128, 0, 0);
    // layer 2: 128 -> 32, written into fuse at column offset (row-major)
    knn(xA, 128, 16);
    phA(xA, 128, 128, 32, Wl[2], bl[2], gl[2], Bl[2]);
    k_phaseB<false,false><<<BD*ND/4, 256, 0, stream>>>(zs, cvb, idxb, fuse, nullptr, 32, 64, part*32);
  }
  // MHA (flash-decode, no-max exp) over all 16 batches
  k_lin<<<BD*32, 256, 0, stream>>>(fuse, mha_wi, mha_bi, qkv);
  k_attn_part<<<BD*4*KSL, 256, 0, stream>>>(qkv, plb, paccb);
  k_attn_comb<<<(BD*8*ND)/256, 256, 0, stream>>>(plb, paccb, attno);
  k_projmean<<<(BD*ND*32)/256, 256, 0, stream>>>(attno, mha_wo, mha_bo, emb);
  // fused attention pool (sout slices are contiguous across the 16 batches)
  k_poolfuse<<<BD, 256, 0, stream>>>(emb, att_w, out + 8, pooled);
  k_head<<<1, 256, 0, stream>>>(pooled, pooled + 256, ntn_w, ntn_v, ntn_b,
                                fc1_w, fc1_b, sc_w, sc_b, out);
}